// Round 14
// baseline (171.711 us; speedup 1.0000x reference)
//
#include <hip/hip_runtime.h>
#include <math.h>

#define SEQL   2048
#define NBATCH 2
#define DMODEL 768
#define DINNER 1536
#define D2     3072
#define DSTATE 16
#define DHID   384
#define ROWS   (NBATCH*SEQL)   /* 4096 */
#define NC     64              /* scan chunks */
#define CL     32              /* chunk length */
#define CROWS  16              /* conv rows per thread */
#define LN_EPSF 1e-5f

typedef unsigned short u16;
typedef short bf16x8 __attribute__((ext_vector_type(8)));
typedef float f32x4 __attribute__((ext_vector_type(4)));

// fp32 -> bf16 round-to-nearest-even
__device__ __forceinline__ u16 f2b(float x) {
  unsigned u = __float_as_uint(x);
  unsigned r = (u + 0x7FFFu + ((u >> 16) & 1u)) >> 16;
  return (u16)r;
}
__device__ __forceinline__ float b2f(u16 v) {
  return __uint_as_float((unsigned)v << 16);
}

// E[n] = exp(-dl)^(n+1), n=0..15 — 1 exp + 15 muls (log-depth ladder).
// Valid when A[d][n] == -(n+1) (device-verified via flag).
__device__ __forceinline__ void build_E_fast(float dl, float* E) {
  float e1 = __expf(-dl);
  float e2 = e1 * e1, e4 = e2 * e2, e8 = e4 * e4;
  E[0] = e1;      E[1] = e2;      E[2] = e2 * e1; E[3] = e4;
  E[4] = e4 * e1; E[5] = e4 * e2; E[6] = e4 * E[2]; E[7] = e8;
  E[8] = e8 * e1; E[9] = e8 * e2; E[10] = e8 * E[2]; E[11] = e8 * e4;
  E[12] = e8 * E[4]; E[13] = e8 * E[5]; E[14] = e8 * E[6]; E[15] = e8 * e8;
}

// ---------------- combined prep kernel (vectorized) -------------------------
// 64x64 transpose tile: float4 reads (1KB/wave-instr), ushort4 writes.
__device__ __forceinline__ void tconv64_body(const float* __restrict__ src,
    u16* __restrict__ dst, int K, int N, int bx, int by, int tid) {
  __shared__ float t[64][65];
  int n0 = bx * 64, k0 = by * 64;
  int tx = tid & 15, ty = tid >> 4;   // 16 x 16
  #pragma unroll
  for (int i = 0; i < 4; ++i) {
    float4 v = *(const float4*)&src[(long)(k0 + ty + 16 * i) * N + n0 + tx * 4];
    t[ty + 16 * i][tx * 4 + 0] = v.x; t[ty + 16 * i][tx * 4 + 1] = v.y;
    t[ty + 16 * i][tx * 4 + 2] = v.z; t[ty + 16 * i][tx * 4 + 3] = v.w;
  }
  __syncthreads();
  #pragma unroll
  for (int i = 0; i < 4; ++i) {
    int n = ty + 16 * i;
    u16 o[4];
    #pragma unroll
    for (int j = 0; j < 4; ++j) o[j] = f2b(t[tx * 4 + j][n]);
    *(ushort4*)&dst[(long)(n0 + n) * K + k0 + tx * 4] = *(ushort4*)o;
  }
}

// Block ranges (2849 blocks x 256 threads):
//  [0,576)     : W_in  [768][3072]  -> Wt_in  bf16   (64x64 tiles)
//  [576,720)   : Wc2   [384][1536]  -> Wt_c2  bf16
//  [720,1008)  : W_out [1536][768]  -> Wt_out bf16
//  [1008,1056) : W_x -> Wxt [64][1536] bf16 zero-pad (bf16x8 stores)
//  [1056,1824) : hid = relu(imp*Wc1+bc1), 8 elems/thread
//  [1824,2848) : LayerNorm, wave-per-row x4 rows/block (shfl-only reduce)
//  2848        : Af = -exp(A_log) + structure flag
__global__ __launch_bounds__(256) void prep_kernel(
    const float* __restrict__ W_in,  u16* __restrict__ Wt_in,
    const float* __restrict__ Wc2,   u16* __restrict__ Wt_c2,
    const float* __restrict__ W_out, u16* __restrict__ Wt_out,
    const float* __restrict__ Wx,    u16* __restrict__ Wxt,
    const float* __restrict__ imp,   const float* __restrict__ Wc1,
    const float* __restrict__ bc1,   u16* __restrict__ hid,
    const float* __restrict__ x,     const float* __restrict__ g,
    const float* __restrict__ bta,   u16* __restrict__ xn,
    const float* __restrict__ A_log, float* __restrict__ Af,
    int* __restrict__ flag) {
  int id = blockIdx.x;
  int tid = threadIdx.x;
  if (id < 576) {
    tconv64_body(W_in, Wt_in, 768, 3072, id % 48, id / 48, tid);
  } else if (id < 720) {
    int r = id - 576;  tconv64_body(Wc2, Wt_c2, 384, 1536, r % 24, r / 24, tid);
  } else if (id < 1008) {
    int r = id - 720;  tconv64_body(W_out, Wt_out, 1536, 768, r % 12, r / 12, tid);
  } else if (id < 1056) {
    long i8 = ((long)(id - 1008) * 256 + tid) * 8;   // over 64*1536
    int n = (int)(i8 / 1536), k0 = (int)(i8 % 1536);
    u16 o[8];
    #pragma unroll
    for (int j = 0; j < 8; ++j)
      o[j] = (n < 33) ? f2b(Wx[(long)(k0 + j) * 33 + n]) : (u16)0;
    *(bf16x8*)&Wxt[i8] = *(bf16x8*)o;
  } else if (id < 1824) {
    long g8 = ((long)(id - 1056) * 256 + tid) * 8;   // over ROWS*DHID
    int j0 = (int)(g8 % DHID);
    long r = g8 / DHID;
    float im = imp[r];
    float4 wa = *(const float4*)&Wc1[j0], wb = *(const float4*)&Wc1[j0 + 4];
    float4 ba = *(const float4*)&bc1[j0], bb = *(const float4*)&bc1[j0 + 4];
    float v[8] = { fmaf(im, wa.x, ba.x), fmaf(im, wa.y, ba.y),
                   fmaf(im, wa.z, ba.z), fmaf(im, wa.w, ba.w),
                   fmaf(im, wb.x, bb.x), fmaf(im, wb.y, bb.y),
                   fmaf(im, wb.z, bb.z), fmaf(im, wb.w, bb.w) };
    u16 o[8];
    #pragma unroll
    for (int j = 0; j < 8; ++j) o[j] = f2b(v[j] > 0.f ? v[j] : 0.f);
    *(bf16x8*)&hid[g8] = *(bf16x8*)o;
  } else if (id < 2848) {
    // LN: wave per row, 4 rows per block; shfl-only reduce, all lanes active
    int wid2 = tid >> 6, lane = tid & 63;
    long r = (long)(id - 1824) * 4 + wid2;
    const float* xr = x + r * DMODEL;
    float vv[12];
    *(float4*)&vv[0] = *(const float4*)&xr[lane * 4];
    *(float4*)&vv[4] = *(const float4*)&xr[lane * 4 + 256];
    *(float4*)&vv[8] = *(const float4*)&xr[lane * 4 + 512];
    float s = 0.f;
    #pragma unroll
    for (int i = 0; i < 12; ++i) s += vv[i];
    #pragma unroll
    for (int o = 32; o > 0; o >>= 1) s += __shfl_xor(s, o);
    float mu = s * (1.f / DMODEL);
    float q = 0.f;
    #pragma unroll
    for (int i = 0; i < 12; ++i) { float dd = vv[i] - mu; q += dd * dd; }
    #pragma unroll
    for (int o = 32; o > 0; o >>= 1) q += __shfl_xor(q, o);
    float rs = rsqrtf(q * (1.f / DMODEL) + LN_EPSF);
    #pragma unroll
    for (int gq = 0; gq < 3; ++gq) {
      int col = lane * 4 + gq * 256;
      float4 gv = *(const float4*)&g[col];
      float4 bv = *(const float4*)&bta[col];
      u16 o[4];
      o[0] = f2b((vv[gq * 4 + 0] - mu) * rs * gv.x + bv.x);
      o[1] = f2b((vv[gq * 4 + 1] - mu) * rs * gv.y + bv.y);
      o[2] = f2b((vv[gq * 4 + 2] - mu) * rs * gv.z + bv.z);
      o[3] = f2b((vv[gq * 4 + 3] - mu) * rs * gv.w + bv.w);
      *(ushort4*)&xn[r * DMODEL + col] = *(ushort4*)o;
    }
  } else {
    __shared__ int scnt;
    if (tid == 0) scnt = 0;
    __syncthreads();
    int mism = 0;
    for (int i = tid; i < DINNER * 16; i += 256) {
      int n = i & 15;
      float a = -expf(A_log[i]);
      Af[i] = a;
      mism += (fabsf(a + (float)(n + 1)) > 1e-3f) ? 1 : 0;
    }
    atomicAdd(&scnt, mism);
    __syncthreads();
    if (tid == 0) *flag = scnt;
  }
}

// ---------------- big-tile xz GEMM: 256x192 tile, 512 threads, 8 waves ------
// xzb[4096][3072] bf16 = xnb[4096][768] @ Wt_in[3072][768]^T, BK=64.
// Staging traffic 175MB (vs 302MB at 128^2); grid = 16x16 = 256 blocks
// (1/CU exactly). Same pre-swizzled global_load_lds staging + 2-phase dbuf.
// Chunked XCD swizzle: 32 consecutive bids/XCD -> A-panel 0.8MB L2-resident.
__global__ __launch_bounds__(512) void gemm_xz_256(
    const u16* __restrict__ A, const u16* __restrict__ Bt,
    u16* __restrict__ pz) {
  constexpr int BM = 256, BN = 192, K = 768, N = 3072;
  constexpr int HALF = (BM + BN) * 128;   // 57344 B per buffer
  __shared__ __align__(16) char smem[2 * HALF];   // 112 KB

  int tid = threadIdx.x;
  int lane = tid & 63;
  int wid = tid >> 6;                 // 0..7
  int bid = blockIdx.y * 16 + blockIdx.x;
  int swz = (bid & 7) * 32 + (bid >> 3);    // bijective, 32 bids/XCD
  int bx = swz & 15, by = swz >> 4;
  int m0 = by * BM, n0 = bx * BN;
  int wr = wid >> 2, wc = wid & 3;    // 2 x 4 wave grid; per-wave 128x48

  f32x4 acc[8][3];
  #pragma unroll
  for (int i = 0; i < 8; ++i)
    #pragma unroll
    for (int j = 0; j < 3; ++j) acc[i][j] = f32x4{0.f, 0.f, 0.f, 0.f};

  int srow = tid >> 3;                // 0..63 (row within staging round)
  int schunk = tid & 7;
  int wavebase = wid * 1024;          // wave-uniform LDS byte base
  int arow = lane & 15;
  int kgrp = lane >> 4;
  int sw = (lane & 7) << 4;

  auto stage = [&](int k0, char* base) {
    #pragma unroll
    for (int r = 0; r < 4; ++r) {     // A: 256 rows, 64 rows/round
      int row = r * 64 + srow;
      int chunk = schunk ^ (row & 7);
      const u16* g = A + (size_t)(m0 + row) * K + k0 + chunk * 8;
      __builtin_amdgcn_global_load_lds(
          (const __attribute__((address_space(1))) void*)g,
          (__attribute__((address_space(3))) void*)(base + r * 8192 + wavebase),
          16, 0, 0);
    }
    #pragma unroll
    for (int r = 0; r < 3; ++r) {     // B: 192 rows
      int row = r * 64 + srow;
      int chunk = schunk ^ (row & 7);
      const u16* g = Bt + (size_t)(n0 + row) * K + k0 + chunk * 8;
      __builtin_amdgcn_global_load_lds(
          (const __attribute__((address_space(1))) void*)g,
          (__attribute__((address_space(3))) void*)(base + BM * 128 + r * 8192 + wavebase),
          16, 0, 0);
    }
  };

  auto compute = [&](const char* base) {
    const char* Asm = base;
    const char* Bsm = base + BM * 128;
    #pragma unroll
    for (int ks = 0; ks < 2; ++ks) {
      bf16x8 af[8], bg[3];
      #pragma unroll
      for (int i = 0; i < 8; ++i) {
        int row = wr * 128 + i * 16 + arow;
        int off = row * 128 + ((((ks * 4 + kgrp) * 16)) ^ sw);
        af[i] = *(const bf16x8*)(Asm + off);
      }
      #pragma unroll
      for (int j = 0; j < 3; ++j) {
        int row = wc * 48 + j * 16 + arow;
        int off = row * 128 + ((((ks * 4 + kgrp) * 16)) ^ sw);
        bg[j] = *(const bf16x8*)(Bsm + off);
      }
      #pragma unroll
      for (int i = 0; i < 8; ++i)
        #pragma unroll
        for (int j = 0; j < 3; ++j)
          acc[i][j] = __builtin_amdgcn_mfma_f32_16x16x32_bf16(af[i], bg[j], acc[i][j], 0, 0, 0);
    }
  };

  stage(0, smem);
  asm volatile("s_waitcnt vmcnt(0)" ::: "memory");
  __builtin_amdgcn_s_barrier();
  #pragma unroll 1
  for (int t = 0; t < 12; t += 2) {
    stage((t + 1) << 6, smem + HALF);
    compute(smem);
    asm volatile("s_waitcnt vmcnt(0)" ::: "memory");
    __builtin_amdgcn_s_barrier();
    if (t + 2 < 12) stage((t + 2) << 6, smem);
    compute(smem + HALF);
    asm volatile("s_waitcnt vmcnt(0)" ::: "memory");
    __builtin_amdgcn_s_barrier();
  }

  int crow0 = m0 + wr * 128 + (lane >> 4) * 4;
  int ccol0 = n0 + wc * 48 + (lane & 15);
  #pragma unroll
  for (int i = 0; i < 8; ++i) {
    #pragma unroll
    for (int r = 0; r < 4; ++r) {
      int row = crow0 + i * 16 + r;
      #pragma unroll
      for (int j = 0; j < 3; ++j) {
        int col = ccol0 + j * 16;
        pz[(size_t)row * N + col] = f2b(acc[i][j][r]);
      }
    }
  }
}

// ---------------- bf16 MFMA GEMM: C[M][N] fp32 = A[M][K]bf16 @ Bt[N][K]bf16 --
// BM x BN tile, BK=64, 256 threads (4 waves, WGM x WGN wave grid).
// LDS layout [rows][64] bf16, XOR-swizzled: byte ^= ((row&7)<<4); staging
// pre-swizzles the *global* source so global_load_lds's linear write lands
// the swizzled layout (m173/m201 pattern).
// DOUBLE-BUFFERED 2-phase pipeline (T3 minimum template, m248-verified).
// XSWZ=1: chunked XCD swizzle (consecutive bids -> same XCD; A-panel + B
// working set fits the 4MB XCD-L2). Use when staging-BW-bound & nwg%8==0.
// EPI: 0 = plain fp32
//      1 = +aux residual (fp32)
//      2 = delta epilogue -> pz bf16 (p1=W_dt, p2=b_dt, p3=bc2, aux=xs64)
//      5 = full bf16 write -> pz
template<int BM, int BN, int WGM, int WGN, int EPI, int XSWZ>
__global__ __launch_bounds__(256) void gemm_bf16(
    const u16* __restrict__ A, const u16* __restrict__ Bt,
    float* __restrict__ C, int M, int N, int K, const float* __restrict__ aux,
    const float* __restrict__ p1, const float* __restrict__ p2,
    const float* __restrict__ p3, u16* __restrict__ pz) {
  constexpr int MF = BM / (16 * WGM);
  constexpr int NF = BN / (16 * WGN);
  constexpr int AR = BM / 32;   // A staging rounds
  constexpr int BR = BN / 32;   // B staging rounds
  constexpr int HALF = (BM + BN) * 128;   // bytes per buffer
  __shared__ __align__(16) char smem[2 * HALF];

  int tid = threadIdx.x;
  int lane = tid & 63;
  int wid = tid >> 6;

  int bx, by;
  if (XSWZ) {
    int nwgx = gridDim.x;
    int bid = blockIdx.y * nwgx + blockIdx.x;
    int nwg = nwgx * gridDim.y;
    int q = nwg >> 3;
    int swz = (bid & 7) * q + (bid >> 3);
    bx = swz % nwgx; by = swz / nwgx;
  } else {
    bx = blockIdx.x; by = blockIdx.y;
  }
  int m0 = by * BM, n0 = bx * BN;
  int wr = wid / WGN, wc = wid % WGN;

  f32x4 acc[MF][NF];
  #pragma unroll
  for (int i = 0; i < MF; ++i)
    #pragma unroll
    for (int j = 0; j < NF; ++j) acc[i][j] = f32x4{0.f, 0.f, 0.f, 0.f};

  int srow = tid >> 3;            // 0..31 within a staging round
  int schunk = tid & 7;           // LDS 16B-chunk index within row
  int wavebase = (tid & 192) * 16;   // wave-uniform LDS byte base (wid*1024)
  int arow = lane & 15;
  int kgrp = lane >> 4;           // 0..3
  int sw = (lane & 7) << 4;       // read-side XOR swizzle

  // stage tile (k-offset k0) into LDS buffer `base`
  auto stage = [&](int k0, char* base) {
    #pragma unroll
    for (int r = 0; r < AR; ++r) {
      int row = r * 32 + srow;
      int chunk = schunk ^ (row & 7);
      const u16* g = A + (size_t)(m0 + row) * K + k0 + chunk * 8;
      __builtin_amdgcn_global_load_lds(
          (const __attribute__((address_space(1))) void*)g,
          (__attribute__((address_space(3))) void*)(base + r * 4096 + wavebase),
          16, 0, 0);
    }
    #pragma unroll
    for (int r = 0; r < BR; ++r) {
      int row = r * 32 + srow;
      int chunk = schunk ^ (row & 7);
      const u16* g = Bt + (size_t)(n0 + row) * K + k0 + chunk * 8;
      __builtin_amdgcn_global_load_lds(
          (const __attribute__((address_space(1))) void*)g,
          (__attribute__((address_space(3))) void*)(base + BM * 128 + r * 4096 + wavebase),
          16, 0, 0);
    }
  };

  // MFMA over one staged K-tile in buffer `base`
  auto compute = [&](const char* base) {
    const char* Asm = base;
    const char* Bsm = base + BM * 128;
    #pragma unroll
    for (int ks = 0; ks < 2; ++ks) {
      bf16x8 af[MF], bg[NF];
      #pragma unroll
      for (int i = 0; i < MF; ++i) {
        int row = wr * MF * 16 + i * 16 + arow;
        int off = row * 128 + ((((ks * 4 + kgrp) * 16)) ^ sw);
        af[i] = *(const bf16x8*)(Asm + off);
      }
      #pragma unroll
      for (int j = 0; j < NF; ++j) {
        int row = wc * NF * 16 + j * 16 + arow;
        int off = row * 128 + ((((ks * 4 + kgrp) * 16)) ^ sw);
        bg[j] = *(const bf16x8*)(Bsm + off);
      }
      #pragma unroll
      for (int i = 0; i < MF; ++i)
        #pragma unroll
        for (int j = 0; j < NF; ++j)
          acc[i][j] = __builtin_amdgcn_mfma_f32_16x16x32_bf16(af[i], bg[j], acc[i][j], 0, 0, 0);
    }
  };

  int nk = K >> 6;   // even for all call sites
  stage(0, smem);
  asm volatile("s_waitcnt vmcnt(0)" ::: "memory");
  __builtin_amdgcn_s_barrier();
  for (int t = 0; t < nk; t += 2) {
    stage((t + 1) << 6, smem + HALF);        // prefetch t+1 (t+1<nk: nk even)
    compute(smem);                            // tile t
    asm volatile("s_waitcnt vmcnt(0)" ::: "memory");
    __builtin_amdgcn_s_barrier();
    if (t + 2 < nk) stage((t + 2) << 6, smem);  // prefetch t+2
    compute(smem + HALF);                     // tile t+1
    asm volatile("s_waitcnt vmcnt(0)" ::: "memory");
    __builtin_amdgcn_s_barrier();
  }

  // epilogue: D row=(lane>>4)*4+r, col=lane&15 (m89-verified)
  int crow0 = m0 + wr * MF * 16 + (lane >> 4) * 4;
  int ccol0 = n0 + wc * NF * 16 + (lane & 15);
  #pragma unroll
  for (int i = 0; i < MF; ++i) {
    #pragma unroll
    for (int r = 0; r < 4; ++r) {
      int row = crow0 + i * 16 + r;
      float araw = 0.f;
      if (EPI == 2) araw = aux[(size_t)row * 64];
      #pragma unroll
      for (int j = 0; j < NF; ++j) {
        int col = ccol0 + j * 16;
        float v = acc[i][j][r];
        if (EPI == 0) {
          C[(size_t)row * N + col] = v;
        } else if (EPI == 1) {
          C[(size_t)row * N + col] = v + aux[(size_t)row * N + col];
        } else if (EPI == 2) {
          float raw = fmaf(araw, p1[col], p2[col]);
          float sp = fmaxf(raw, 0.f) + __logf(1.f + __expf(-fabsf(raw)));
          float mod = 1.f / (1.f + __expf(-(v + p3[col])));
          pz[(size_t)row * N + col] = f2b(sp * (1.f + mod));
        } else if (EPI == 5) {
          pz[(size_t)row * N + col] = f2b(v);
        }
      }
    }
  }
}

// ---------------- 3. depthwise causal conv (k=4) + bias + SiLU ---------------
// Rolling-window: thread owns fixed d, walks CROWS s-steps; each xzb element
// read exactly once (vs 4x), coalesced across lanes. 1536 blocks.
__global__ __launch_bounds__(256) void conv_silu_kernel(const u16* __restrict__ xzb,
    const float* __restrict__ cw, const float* __restrict__ cb,
    u16* __restrict__ xcb) {
  int tid = threadIdx.x;
  int dblk = blockIdx.x % (DINNER / 256);     // 6
  int rc   = blockIdx.x / (DINNER / 256);     // 0..255
  int d = dblk * 256 + tid;
  long r0 = (long)rc * CROWS;                 // chunks never cross batch (2048%16==0)
  int s0 = (int)(r0 % SEQL);
  const u16* xp = xzb + r0 * D2 + d;
  float w0 = 0.f, w1 = 0.f, w2 = 0.f;
  if (s0 >= 1) {
    w2 = b2f(xp[-1L * D2]);
    w1 = b2f(xp[-2L * D2]);
    w0 = b2f(xp[-3L * D2]);
  }
  float c0 = cw[d * 4 + 0], c1 = cw[d * 4 + 1];
  float c2 = cw[d * 4 + 2], c3 = cw[d * 4 + 3];
  float cbv = cb[d];
  u16* yp = xcb + r0 * DINNER + d;
  #pragma unroll 4
  for (int t = 0; t < CROWS; ++t) {
    float w3 = b2f(xp[(long)t * D2]);
    float acc = fmaf(w0, c0, fmaf(w1, c1, fmaf(w2, c2, fmaf(w3, c3, cbv))));
    float sg = 1.f / (1.f + __expf(-acc));
    yp[(long)t * DINNER] = f2b(acc * sg);
    w0 = w1; w1 = w2; w2 = w3;
  }
}

// ---------------- 7. scan phase 1: per-chunk local states + sum(delta) ------
__global__ __launch_bounds__(256) void scan_p1(const u16* __restrict__ dlt,
    const u16* __restrict__ xc, const float* __restrict__ xs,
    const float* __restrict__ Af, const int* __restrict__ flag,
    float* __restrict__ Hloc, float* __restrict__ sdl) {
  __shared__ float Bsh[CL][16];
  int tid = threadIdx.x;
  int dblk = blockIdx.x % (DINNER / 256);
  int c = (blockIdx.x / (DINNER / 256)) % NC;
  int b = blockIdx.x / ((DINNER / 256) * NC);
  int d = dblk * 256 + tid;
  long row0 = (long)b * SEQL + c * CL;
  for (int e = tid; e < CL * 16; e += 256) {
    int t = e >> 4, n = e & 15;
    Bsh[t][n] = xs[(row0 + t) * 64 + 1 + n];
  }
  bool fast = (*flag == 0);
  float Ac[16];
  if (!fast) {
    #pragma unroll
    for (int n = 0; n < 16; ++n) Ac[n] = Af[d * 16 + n];
  }
  __syncthreads();
  float h[16] = {};
  float sd = 0.f;
  const u16* dp = dlt + row0 * DINNER + d;
  const u16* xp = xc + row0 * DINNER + d;
  if (fast) {
    for (int t = 0; t < CL; ++t) {
      float dl = b2f(dp[(long)t * DINNER]);
      float xv = b2f(xp[(long)t * DINNER]);
      sd += dl;
      float dx = dl * xv;
      float E[16]; build_E_fast(dl, E);
      #pragma unroll
      for (int n = 0; n < 16; ++n) h[n] = fmaf(E[n], h[n], dx * Bsh[t][n]);
    }
  } else {
    for (int t = 0; t < CL; ++t) {
      float dl = b2f(dp[(long)t * DINNER]);
      float xv = b2f(xp[(long)t * DINNER]);
      sd += dl;
      float dx = dl * xv;
      #pragma unroll
      for (int n = 0; n < 16; ++n)
        h[n] = fmaf(__expf(dl * Ac[n]), h[n], dx * Bsh[t][n]);
    }
  }
  long base = ((long)(b * NC + c) * DINNER + d) * 16;
  #pragma unroll
  for (int n = 0; n < 16; ++n) Hloc[base + n] = h[n];
  sdl[(long)(b * NC + c) * DINNER + d] = sd;
}

// ---------------- 8. scan phase 2: carry sweep (64-thread blocks, 3/CU) ------
__global__ __launch_bounds__(64) void scan_carry(float* __restrict__ Hloc,
    const float* __restrict__ sdl, const float* __restrict__ Af) {
  long g = (long)blockIdx.x * 64 + threadIdx.x;   // over 2*1536*16 = 49152
  int n = (int)(g & 15);
  int d = (int)((g >> 4) % DINNER);
  int b = (int)(g / (16L * DINNER));
  float An = Af[d * 16 + n];
  float s = 0.f;
  for (int c = 0; c < NC; ++c) {
    long off = ((long)(b * NC + c) * DINNER + d) * 16 + n;
    float H = Hloc[off];
    float sdv = sdl[(long)(b * NC + c) * DINNER + d];
    Hloc[off] = s;
    s = fmaf(__expf(An * sdv), s, H);
  }
}

// ---------------- 9. scan phase 3: replay + fused gate -> y2 (bf16) ----------
__global__ __launch_bounds__(256) void scan_p3(const u16* __restrict__ dlt,
    const u16* __restrict__ xc, const float* __restrict__ xs,
    const float* __restrict__ Af, const int* __restrict__ flag,
    const float* __restrict__ Hloc, const u16* __restrict__ xzb,
    const float* __restrict__ Dskip, u16* __restrict__ y2) {
  __shared__ float Bsh[CL][16];
  __shared__ float Csh[CL][16];
  int tid = threadIdx.x;
  int dblk = blockIdx.x % (DINNER / 256);
  int c = (blockIdx.x / (DINNER / 256)) % NC;
  int b = blockIdx.x / ((DINNER / 256) * NC);
  int d = dblk * 256 + tid;
  long row0 = (long)b * SEQL + c * CL;
  for (int e = tid; e < CL * 16; e += 256) {
    int t = e >> 4, n = e & 15;
    long rr = row0 + t;
    Bsh[t][n] = xs[rr * 64 + 1 + n];
    Csh[t][n] = xs[rr * 64 + 17 + n];
  }
  bool fast = (*flag == 0);
  float Ac[16];
  if (!fast) {
    #pragma unroll
    for (int n = 0; n < 16; ++n) Ac[n] = Af[d * 16 + n];
  }
  __syncthreads();
  float h[16];
  long base = ((long)(b * NC + c) * DINNER + d) * 16;
  #pragma unroll
  for (int n = 0; n < 16; ++n) h[n] = Hloc[base + n];
  float Dv = Dskip[d];
  const u16* dp = dlt + row0 * DINNER + d;
  const u16* xp = xc + row0 * DINNER + d;
  const u16* zp = xzb + row0 * D2 + DINNER + d;   // z = cols 1536.. of xzb
  u16* yp = y2 + row0 * DINNER + d;
  if (fast) {
    for (int t = 0; t < CL; ++t) {
      float dl = b2f(dp[(long)t * DINNER]);
      float xv = b2f(xp[(long)t * DINNER]);
      float dx = dl * xv;
      float E[16]; build_E_fast(dl, E);
      float y = 0.f;
      #pragma unroll
      for (int n = 0; n < 16; ++n) {
        h[n] = fmaf(E[n], h[n], dx * Bsh[t][n]);
        y = fmaf(h[n], Csh[t][n], y);
      }
      float yv = fmaf(xv, Dv, y);
      float zv = b2f(zp[(long)t * D2]);
      float sz = zv / (1.f + __expf(-zv));
      yp[(long)t * DINNER] = f2b(yv * sz);
    }
  } else {
    for (int t = 0; t < CL; ++t) {
      float dl = b2f(dp[(long)t * DINNER]);
      float xv = b2f(xp[(long)t * DINNER]);
      float dx = dl * xv;
      float y = 0.f;
      #pragma unroll
      for (int n = 0; n < 16; ++n) {
        h[n] = fmaf(__expf(dl * Ac[n]), h[n], dx * Bsh[t][n]);
        y = fmaf(h[n], Csh[t][n], y);
      }
      float yv = fmaf(xv, Dv, y);
      float zv = b2f(zp[(long)t * D2]);
      float sz = zv / (1.f + __expf(-zv));
      yp[(long)t * DINNER] = f2b(yv * sz);
    }
  }
}

// ---------------- launch ----------------
extern "C" void kernel_launch(void* const* d_in, const int* in_sizes, int n_in,
                              void* d_out, int out_size, void* d_ws, size_t ws_size,
                              hipStream_t stream) {
  const float* x      = (const float*)d_in[0];
  const float* imp    = (const float*)d_in[1];
  const float* ln_g   = (const float*)d_in[2];
  const float* ln_b   = (const float*)d_in[3];
  const float* W_in   = (const float*)d_in[4];
  const float* conv_w = (const float*)d_in[5];
  const float* conv_b = (const float*)d_in[6];
  const float* W_x    = (const float*)d_in[7];
  const float* W_dt   = (const float*)d_in[8];
  const float* b_dt   = (const float*)d_in[9];
  const float* Wc1    = (const float*)d_in[10];
  const float* bc1    = (const float*)d_in[11];
  const float* Wc2    = (const float*)d_in[12];
  const float* bc2    = (const float*)d_in[13];
  const float* A_log  = (const float*)d_in[14];
  const float* Dskip  = (const float*)d_in[15];
  const float* W_out  = (const float*)d_in[16];
  float* out = (float*)d_out;

  char* ws = (char*)d_ws;
  u16*   xzb    = (u16*)  (ws);                 // 4096*3072 bf16  (25165824)
  u16*   xcb    = (u16*)  (ws + 25165824L);     // 4096*1536 bf16  (12582912)
  u16*   dltb   = (u16*)  (ws + 37748736L);     // 4096*1536 bf16  (12582912)
  float* xs64   = (float*)(ws + 50331648L);     // 4096*64 f32     (1048576)
  u16*   hid    = (u16*)  (ws + 51380224L);     // 4096*384 bf16   (3145728)
  u16*   xnb    = (u16*)  (ws + 54525952L);     // 4096*768 bf16   (6291456)
  u16*   y2     = (u16*)  (ws + 60817408L);     // 4096*1536 bf16  (12582912)
  float* Hloc   = (float*)(ws + 73400320L);     // 2*64*1536*16 f32 (12582912)
  float* sdl    = (float*)(ws + 85983232L);     // 2*64*1536 f32   (786432)
  u16*   Wt_in  = (u16*)  (ws + 86769664L);     // 3072*768 bf16   (4718592)
  u16*   Wt_c2  = (u16*)  (ws + 91488256L);     // 1536*384 bf16   (1179648)
  u16*   Wt_out = (u16*)  (ws + 92667904L);     // 768*1536 bf16   (2359296)
  u16*   Wxt    = (u16*)  (ws + 95027200L);     // 64*1536 bf16    (196608)
  float* Af     = (float*)(ws + 95223808L);     // 1536*16 f32     (98304)
  int*   flag   = (int*)  (ws + 95322112L);     // 4

  // 0. combined prep (vectorized): weight transposes + wxt + hid + LN + Af
  prep_kernel<<<2849, 256, 0, stream>>>(
      W_in, Wt_in, Wc2, Wt_c2, W_out, Wt_out, W_x, Wxt,
      imp, Wc1, bc1, hid, x, ln_g, ln_b, xnb, A_log, Af, flag);

  // 2. xz = xn @ W_in (4096 x 768 x 3072) -> xzb bf16 (x_proj | z)
  //    256x192 big tile, 512 threads, 256 blocks (1/CU)
  gemm_xz_256<<<dim3(16, 16), 512, 0, stream>>>(xnb, Wt_in, xzb);
  // 3. conv + SiLU -> xcb (bf16), rolling-window (single read of xzb)
  conv_silu_kernel<<<(DINNER / 256) * (ROWS / CROWS), 256, 0, stream>>>(xzb, conv_w, conv_b, xcb);
  // 4. x_ssm = xc @ W_x  (MFMA, N padded 33->64) -> xs64   (BM=32: 128 blocks)
  gemm_bf16<32,64,1,4,0,0><<<dim3(1, ROWS/32), 256, 0, stream>>>(
      xcb, Wxt, xs64, ROWS, 64, DINNER, nullptr, nullptr, nullptr, nullptr, nullptr);
  // 6. dlt = softplus(xs64[:,0]*Wdt+bdt) * (1+sigmoid(hid@Wc2 + bc2)) -> bf16
  //    128x128 tile (staging 113->76MB), chunked XCD swizzle (384 blocks)
  gemm_bf16<128,128,2,2,2,1><<<dim3(DINNER/128, ROWS/128), 256, 0, stream>>>(
      hid, Wt_c2, nullptr, ROWS, DINNER, DHID, xs64, W_dt, b_dt, bc2, dltb);
  // 7-9. chunked scan (NC=64, CL=32)
  scan_p1<<<NBATCH * NC * (DINNER / 256), 256, 0, stream>>>(dltb, xcb, xs64, Af, flag, Hloc, sdl);
  scan_carry<<<(NBATCH * DINNER * 16) / 64, 64, 0, stream>>>(Hloc, sdl, Af);
  scan_p3<<<NBATCH * NC * (DINNER / 256), 256, 0, stream>>>(dltb, xcb, xs64, Af, flag, Hloc, xzb, Dskip, y2);
  // 10. out = y2 @ W_out + residual  (4096 x 1536 x 768)
  //     128x96 tile (staging 302->177MB), chunked XCD swizzle (256 blocks)
  gemm_bf16<128,96,2,2,1,1><<<dim3(DMODEL/96, ROWS/128), 256, 0, stream>>>(
      y2, Wt_out, out, ROWS, DMODEL, DINNER, x, nullptr, nullptr, nullptr, nullptr);
}

// Round 15
// 158.998 us; speedup vs baseline: 1.0800x; 1.0800x over previous
//
#include <hip/hip_runtime.h>
#include <math.h>

#define SEQL   2048
#define NBATCH 2
#define DMODEL 768
#define DINNER 1536
#define D2     3072
#define DSTATE 16
#define DHID   384
#define ROWS   (NBATCH*SEQL)   /* 4096 */
#define NC     64              /* scan chunks */
#define CL     32              /* chunk length */
#define CROWS  16              /* conv rows per thread */
#define LN_EPSF 1e-5f

typedef unsigned short u16;
typedef short bf16x8 __attribute__((ext_vector_type(8)));
typedef float f32x4 __attribute__((ext_vector_type(4)));

// fp32 -> bf16 round-to-nearest-even
__device__ __forceinline__ u16 f2b(float x) {
  unsigned u = __float_as_uint(x);
  unsigned r = (u + 0x7FFFu + ((u >> 16) & 1u)) >> 16;
  return (u16)r;
}
__device__ __forceinline__ float b2f(u16 v) {
  return __uint_as_float((unsigned)v << 16);
}

// E[n] = exp(-dl)^(n+1), n=0..15 — 1 exp + 15 muls (log-depth ladder).
// Valid when A[d][n] == -(n+1) (device-verified via flag).
__device__ __forceinline__ void build_E_fast(float dl, float* E) {
  float e1 = __expf(-dl);
  float e2 = e1 * e1, e4 = e2 * e2, e8 = e4 * e4;
  E[0] = e1;      E[1] = e2;      E[2] = e2 * e1; E[3] = e4;
  E[4] = e4 * e1; E[5] = e4 * e2; E[6] = e4 * E[2]; E[7] = e8;
  E[8] = e8 * e1; E[9] = e8 * e2; E[10] = e8 * E[2]; E[11] = e8 * e4;
  E[12] = e8 * E[4]; E[13] = e8 * E[5]; E[14] = e8 * E[6]; E[15] = e8 * e8;
}

// ---------------- combined prep kernel (vectorized) -------------------------
// 64x64 transpose tile: float4 reads (1KB/wave-instr), ushort4 writes.
__device__ __forceinline__ void tconv64_body(const float* __restrict__ src,
    u16* __restrict__ dst, int K, int N, int bx, int by, int tid) {
  __shared__ float t[64][65];
  int n0 = bx * 64, k0 = by * 64;
  int tx = tid & 15, ty = tid >> 4;   // 16 x 16
  #pragma unroll
  for (int i = 0; i < 4; ++i) {
    float4 v = *(const float4*)&src[(long)(k0 + ty + 16 * i) * N + n0 + tx * 4];
    t[ty + 16 * i][tx * 4 + 0] = v.x; t[ty + 16 * i][tx * 4 + 1] = v.y;
    t[ty + 16 * i][tx * 4 + 2] = v.z; t[ty + 16 * i][tx * 4 + 3] = v.w;
  }
  __syncthreads();
  #pragma unroll
  for (int i = 0; i < 4; ++i) {
    int n = ty + 16 * i;
    u16 o[4];
    #pragma unroll
    for (int j = 0; j < 4; ++j) o[j] = f2b(t[tx * 4 + j][n]);
    *(ushort4*)&dst[(long)(n0 + n) * K + k0 + tx * 4] = *(ushort4*)o;
  }
}

// Block ranges (2849 blocks x 256 threads):
//  [0,576)     : W_in  [768][3072]  -> Wt_in  bf16   (64x64 tiles)
//  [576,720)   : Wc2   [384][1536]  -> Wt_c2  bf16
//  [720,1008)  : W_out [1536][768]  -> Wt_out bf16
//  [1008,1056) : W_x -> Wxt [64][1536] bf16 zero-pad (bf16x8 stores)
//  [1056,1824) : hid = relu(imp*Wc1+bc1), 8 elems/thread
//  [1824,2848) : LayerNorm, wave-per-row x4 rows/block (shfl-only reduce)
//  2848        : Af = -exp(A_log) + structure flag
__global__ __launch_bounds__(256) void prep_kernel(
    const float* __restrict__ W_in,  u16* __restrict__ Wt_in,
    const float* __restrict__ Wc2,   u16* __restrict__ Wt_c2,
    const float* __restrict__ W_out, u16* __restrict__ Wt_out,
    const float* __restrict__ Wx,    u16* __restrict__ Wxt,
    const float* __restrict__ imp,   const float* __restrict__ Wc1,
    const float* __restrict__ bc1,   u16* __restrict__ hid,
    const float* __restrict__ x,     const float* __restrict__ g,
    const float* __restrict__ bta,   u16* __restrict__ xn,
    const float* __restrict__ A_log, float* __restrict__ Af,
    int* __restrict__ flag) {
  int id = blockIdx.x;
  int tid = threadIdx.x;
  if (id < 576) {
    tconv64_body(W_in, Wt_in, 768, 3072, id % 48, id / 48, tid);
  } else if (id < 720) {
    int r = id - 576;  tconv64_body(Wc2, Wt_c2, 384, 1536, r % 24, r / 24, tid);
  } else if (id < 1008) {
    int r = id - 720;  tconv64_body(W_out, Wt_out, 1536, 768, r % 12, r / 12, tid);
  } else if (id < 1056) {
    long i8 = ((long)(id - 1008) * 256 + tid) * 8;   // over 64*1536
    int n = (int)(i8 / 1536), k0 = (int)(i8 % 1536);
    u16 o[8];
    #pragma unroll
    for (int j = 0; j < 8; ++j)
      o[j] = (n < 33) ? f2b(Wx[(long)(k0 + j) * 33 + n]) : (u16)0;
    *(bf16x8*)&Wxt[i8] = *(bf16x8*)o;
  } else if (id < 1824) {
    long g8 = ((long)(id - 1056) * 256 + tid) * 8;   // over ROWS*DHID
    int j0 = (int)(g8 % DHID);
    long r = g8 / DHID;
    float im = imp[r];
    float4 wa = *(const float4*)&Wc1[j0], wb = *(const float4*)&Wc1[j0 + 4];
    float4 ba = *(const float4*)&bc1[j0], bb = *(const float4*)&bc1[j0 + 4];
    float v[8] = { fmaf(im, wa.x, ba.x), fmaf(im, wa.y, ba.y),
                   fmaf(im, wa.z, ba.z), fmaf(im, wa.w, ba.w),
                   fmaf(im, wb.x, bb.x), fmaf(im, wb.y, bb.y),
                   fmaf(im, wb.z, bb.z), fmaf(im, wb.w, bb.w) };
    u16 o[8];
    #pragma unroll
    for (int j = 0; j < 8; ++j) o[j] = f2b(v[j] > 0.f ? v[j] : 0.f);
    *(bf16x8*)&hid[g8] = *(bf16x8*)o;
  } else if (id < 2848) {
    // LN: wave per row, 4 rows per block; shfl-only reduce, all lanes active
    int wid2 = tid >> 6, lane = tid & 63;
    long r = (long)(id - 1824) * 4 + wid2;
    const float* xr = x + r * DMODEL;
    float vv[12];
    *(float4*)&vv[0] = *(const float4*)&xr[lane * 4];
    *(float4*)&vv[4] = *(const float4*)&xr[lane * 4 + 256];
    *(float4*)&vv[8] = *(const float4*)&xr[lane * 4 + 512];
    float s = 0.f;
    #pragma unroll
    for (int i = 0; i < 12; ++i) s += vv[i];
    #pragma unroll
    for (int o = 32; o > 0; o >>= 1) s += __shfl_xor(s, o);
    float mu = s * (1.f / DMODEL);
    float q = 0.f;
    #pragma unroll
    for (int i = 0; i < 12; ++i) { float dd = vv[i] - mu; q += dd * dd; }
    #pragma unroll
    for (int o = 32; o > 0; o >>= 1) q += __shfl_xor(q, o);
    float rs = rsqrtf(q * (1.f / DMODEL) + LN_EPSF);
    #pragma unroll
    for (int gq = 0; gq < 3; ++gq) {
      int col = lane * 4 + gq * 256;
      float4 gv = *(const float4*)&g[col];
      float4 bv = *(const float4*)&bta[col];
      u16 o[4];
      o[0] = f2b((vv[gq * 4 + 0] - mu) * rs * gv.x + bv.x);
      o[1] = f2b((vv[gq * 4 + 1] - mu) * rs * gv.y + bv.y);
      o[2] = f2b((vv[gq * 4 + 2] - mu) * rs * gv.z + bv.z);
      o[3] = f2b((vv[gq * 4 + 3] - mu) * rs * gv.w + bv.w);
      *(ushort4*)&xn[r * DMODEL + col] = *(ushort4*)o;
    }
  } else {
    __shared__ int scnt;
    if (tid == 0) scnt = 0;
    __syncthreads();
    int mism = 0;
    for (int i = tid; i < DINNER * 16; i += 256) {
      int n = i & 15;
      float a = -expf(A_log[i]);
      Af[i] = a;
      mism += (fabsf(a + (float)(n + 1)) > 1e-3f) ? 1 : 0;
    }
    atomicAdd(&scnt, mism);
    __syncthreads();
    if (tid == 0) *flag = scnt;
  }
}

// ---------------- big-tile xz GEMM: 256x192 tile, 512 threads, 8 waves ------
// xzb[4096][3072] bf16 = xnb[4096][768] @ Wt_in[3072][768]^T, BK=64.
// Staging traffic 175MB (vs 302MB at 128^2); grid = 16x16 = 256 blocks
// (1/CU exactly). Same pre-swizzled global_load_lds staging + 2-phase dbuf.
// Chunked XCD swizzle: 32 consecutive bids/XCD -> A-panel 0.8MB L2-resident.
__global__ __launch_bounds__(512) void gemm_xz_256(
    const u16* __restrict__ A, const u16* __restrict__ Bt,
    u16* __restrict__ pz) {
  constexpr int BM = 256, BN = 192, K = 768, N = 3072;
  constexpr int HALF = (BM + BN) * 128;   // 57344 B per buffer
  __shared__ __align__(16) char smem[2 * HALF];   // 112 KB

  int tid = threadIdx.x;
  int lane = tid & 63;
  int wid = tid >> 6;                 // 0..7
  int bid = blockIdx.y * 16 + blockIdx.x;
  int swz = (bid & 7) * 32 + (bid >> 3);    // bijective, 32 bids/XCD
  int bx = swz & 15, by = swz >> 4;
  int m0 = by * BM, n0 = bx * BN;
  int wr = wid >> 2, wc = wid & 3;    // 2 x 4 wave grid; per-wave 128x48

  f32x4 acc[8][3];
  #pragma unroll
  for (int i = 0; i < 8; ++i)
    #pragma unroll
    for (int j = 0; j < 3; ++j) acc[i][j] = f32x4{0.f, 0.f, 0.f, 0.f};

  int srow = tid >> 3;                // 0..63 (row within staging round)
  int schunk = tid & 7;
  int wavebase = wid * 1024;          // wave-uniform LDS byte base
  int arow = lane & 15;
  int kgrp = lane >> 4;
  int sw = (lane & 7) << 4;

  auto stage = [&](int k0, char* base) {
    #pragma unroll
    for (int r = 0; r < 4; ++r) {     // A: 256 rows, 64 rows/round
      int row = r * 64 + srow;
      int chunk = schunk ^ (row & 7);
      const u16* g = A + (size_t)(m0 + row) * K + k0 + chunk * 8;
      __builtin_amdgcn_global_load_lds(
          (const __attribute__((address_space(1))) void*)g,
          (__attribute__((address_space(3))) void*)(base + r * 8192 + wavebase),
          16, 0, 0);
    }
    #pragma unroll
    for (int r = 0; r < 3; ++r) {     // B: 192 rows
      int row = r * 64 + srow;
      int chunk = schunk ^ (row & 7);
      const u16* g = Bt + (size_t)(n0 + row) * K + k0 + chunk * 8;
      __builtin_amdgcn_global_load_lds(
          (const __attribute__((address_space(1))) void*)g,
          (__attribute__((address_space(3))) void*)(base + BM * 128 + r * 8192 + wavebase),
          16, 0, 0);
    }
  };

  auto compute = [&](const char* base) {
    const char* Asm = base;
    const char* Bsm = base + BM * 128;
    #pragma unroll
    for (int ks = 0; ks < 2; ++ks) {
      bf16x8 af[8], bg[3];
      #pragma unroll
      for (int i = 0; i < 8; ++i) {
        int row = wr * 128 + i * 16 + arow;
        int off = row * 128 + ((((ks * 4 + kgrp) * 16)) ^ sw);
        af[i] = *(const bf16x8*)(Asm + off);
      }
      #pragma unroll
      for (int j = 0; j < 3; ++j) {
        int row = wc * 48 + j * 16 + arow;
        int off = row * 128 + ((((ks * 4 + kgrp) * 16)) ^ sw);
        bg[j] = *(const bf16x8*)(Bsm + off);
      }
      #pragma unroll
      for (int i = 0; i < 8; ++i)
        #pragma unroll
        for (int j = 0; j < 3; ++j)
          acc[i][j] = __builtin_amdgcn_mfma_f32_16x16x32_bf16(af[i], bg[j], acc[i][j], 0, 0, 0);
    }
  };

  stage(0, smem);
  asm volatile("s_waitcnt vmcnt(0)" ::: "memory");
  __builtin_amdgcn_s_barrier();
  #pragma unroll 1
  for (int t = 0; t < 12; t += 2) {
    stage((t + 1) << 6, smem + HALF);
    compute(smem);
    asm volatile("s_waitcnt vmcnt(0)" ::: "memory");
    __builtin_amdgcn_s_barrier();
    if (t + 2 < 12) stage((t + 2) << 6, smem);
    compute(smem + HALF);
    asm volatile("s_waitcnt vmcnt(0)" ::: "memory");
    __builtin_amdgcn_s_barrier();
  }

  int crow0 = m0 + wr * 128 + (lane >> 4) * 4;
  int ccol0 = n0 + wc * 48 + (lane & 15);
  #pragma unroll
  for (int i = 0; i < 8; ++i) {
    #pragma unroll
    for (int r = 0; r < 4; ++r) {
      int row = crow0 + i * 16 + r;
      #pragma unroll
      for (int j = 0; j < 3; ++j) {
        int col = ccol0 + j * 16;
        pz[(size_t)row * N + col] = f2b(acc[i][j][r]);
      }
    }
  }
}

// ---------------- bf16 MFMA GEMM: C[M][N] fp32 = A[M][K]bf16 @ Bt[N][K]bf16 --
// BM x BN tile, BK=64, 256 threads (4 waves, WGM x WGN wave grid).
// LDS layout [rows][64] bf16, XOR-swizzled: byte ^= ((row&7)<<4); staging
// pre-swizzles the *global* source so global_load_lds's linear write lands
// the swizzled layout (m173/m201 pattern).
// DOUBLE-BUFFERED 2-phase pipeline (T3 minimum template, m248-verified).
// EPI: 0 = plain fp32
//      1 = +aux residual (fp32)
//      2 = delta epilogue -> pz bf16 (p1=W_dt, p2=b_dt, p3=bc2, aux=xs64)
//      5 = full bf16 write -> pz
template<int BM, int BN, int WGM, int WGN, int EPI, int XSWZ>
__global__ __launch_bounds__(256) void gemm_bf16(
    const u16* __restrict__ A, const u16* __restrict__ Bt,
    float* __restrict__ C, int M, int N, int K, const float* __restrict__ aux,
    const float* __restrict__ p1, const float* __restrict__ p2,
    const float* __restrict__ p3, u16* __restrict__ pz) {
  constexpr int MF = BM / (16 * WGM);
  constexpr int NF = BN / (16 * WGN);
  constexpr int AR = BM / 32;   // A staging rounds
  constexpr int BR = BN / 32;   // B staging rounds
  constexpr int HALF = (BM + BN) * 128;   // bytes per buffer
  __shared__ __align__(16) char smem[2 * HALF];

  int tid = threadIdx.x;
  int lane = tid & 63;
  int wid = tid >> 6;

  int bx, by;
  if (XSWZ) {
    int nwgx = gridDim.x;
    int bid = blockIdx.y * nwgx + blockIdx.x;
    int nwg = nwgx * gridDim.y;
    int q = nwg >> 3;
    int swz = (bid & 7) * q + (bid >> 3);
    bx = swz % nwgx; by = swz / nwgx;
  } else {
    bx = blockIdx.x; by = blockIdx.y;
  }
  int m0 = by * BM, n0 = bx * BN;
  int wr = wid / WGN, wc = wid % WGN;

  f32x4 acc[MF][NF];
  #pragma unroll
  for (int i = 0; i < MF; ++i)
    #pragma unroll
    for (int j = 0; j < NF; ++j) acc[i][j] = f32x4{0.f, 0.f, 0.f, 0.f};

  int srow = tid >> 3;            // 0..31 within a staging round
  int schunk = tid & 7;           // LDS 16B-chunk index within row
  int wavebase = (tid & 192) * 16;   // wave-uniform LDS byte base (wid*1024)
  int arow = lane & 15;
  int kgrp = lane >> 4;           // 0..3
  int sw = (lane & 7) << 4;       // read-side XOR swizzle

  // stage tile (k-offset k0) into LDS buffer `base`
  auto stage = [&](int k0, char* base) {
    #pragma unroll
    for (int r = 0; r < AR; ++r) {
      int row = r * 32 + srow;
      int chunk = schunk ^ (row & 7);
      const u16* g = A + (size_t)(m0 + row) * K + k0 + chunk * 8;
      __builtin_amdgcn_global_load_lds(
          (const __attribute__((address_space(1))) void*)g,
          (__attribute__((address_space(3))) void*)(base + r * 4096 + wavebase),
          16, 0, 0);
    }
    #pragma unroll
    for (int r = 0; r < BR; ++r) {
      int row = r * 32 + srow;
      int chunk = schunk ^ (row & 7);
      const u16* g = Bt + (size_t)(n0 + row) * K + k0 + chunk * 8;
      __builtin_amdgcn_global_load_lds(
          (const __attribute__((address_space(1))) void*)g,
          (__attribute__((address_space(3))) void*)(base + BM * 128 + r * 4096 + wavebase),
          16, 0, 0);
    }
  };

  // MFMA over one staged K-tile in buffer `base`
  auto compute = [&](const char* base) {
    const char* Asm = base;
    const char* Bsm = base + BM * 128;
    #pragma unroll
    for (int ks = 0; ks < 2; ++ks) {
      bf16x8 af[MF], bg[NF];
      #pragma unroll
      for (int i = 0; i < MF; ++i) {
        int row = wr * MF * 16 + i * 16 + arow;
        int off = row * 128 + ((((ks * 4 + kgrp) * 16)) ^ sw);
        af[i] = *(const bf16x8*)(Asm + off);
      }
      #pragma unroll
      for (int j = 0; j < NF; ++j) {
        int row = wc * NF * 16 + j * 16 + arow;
        int off = row * 128 + ((((ks * 4 + kgrp) * 16)) ^ sw);
        bg[j] = *(const bf16x8*)(Bsm + off);
      }
      #pragma unroll
      for (int i = 0; i < MF; ++i)
        #pragma unroll
        for (int j = 0; j < NF; ++j)
          acc[i][j] = __builtin_amdgcn_mfma_f32_16x16x32_bf16(af[i], bg[j], acc[i][j], 0, 0, 0);
    }
  };

  int nk = K >> 6;   // even for all call sites
  stage(0, smem);
  asm volatile("s_waitcnt vmcnt(0)" ::: "memory");
  __builtin_amdgcn_s_barrier();
  for (int t = 0; t < nk; t += 2) {
    stage((t + 1) << 6, smem + HALF);        // prefetch t+1 (t+1<nk: nk even)
    compute(smem);                            // tile t
    asm volatile("s_waitcnt vmcnt(0)" ::: "memory");
    __builtin_amdgcn_s_barrier();
    if (t + 2 < nk) stage((t + 2) << 6, smem);  // prefetch t+2
    compute(smem + HALF);                     // tile t+1
    asm volatile("s_waitcnt vmcnt(0)" ::: "memory");
    __builtin_amdgcn_s_barrier();
  }

  // epilogue: D row=(lane>>4)*4+r, col=lane&15 (m89-verified)
  int crow0 = m0 + wr * MF * 16 + (lane >> 4) * 4;
  int ccol0 = n0 + wc * NF * 16 + (lane & 15);
  #pragma unroll
  for (int i = 0; i < MF; ++i) {
    #pragma unroll
    for (int r = 0; r < 4; ++r) {
      int row = crow0 + i * 16 + r;
      float araw = 0.f;
      if (EPI == 2) araw = aux[(size_t)row * 64];
      #pragma unroll
      for (int j = 0; j < NF; ++j) {
        int col = ccol0 + j * 16;
        float v = acc[i][j][r];
        if (EPI == 0) {
          C[(size_t)row * N + col] = v;
        } else if (EPI == 1) {
          C[(size_t)row * N + col] = v + aux[(size_t)row * N + col];
        } else if (EPI == 2) {
          float raw = fmaf(araw, p1[col], p2[col]);
          float sp = fmaxf(raw, 0.f) + __logf(1.f + __expf(-fabsf(raw)));
          float mod = 1.f / (1.f + __expf(-(v + p3[col])));
          pz[(size_t)row * N + col] = f2b(sp * (1.f + mod));
        } else if (EPI == 5) {
          pz[(size_t)row * N + col] = f2b(v);
        }
      }
    }
  }
}

// ---------------- 3. depthwise causal conv (k=4) + bias + SiLU ---------------
// Rolling-window: thread owns fixed d, walks CROWS s-steps; each xzb element
// read exactly once (vs 4x), coalesced across lanes. 1536 blocks.
__global__ __launch_bounds__(256) void conv_silu_kernel(const u16* __restrict__ xzb,
    const float* __restrict__ cw, const float* __restrict__ cb,
    u16* __restrict__ xcb) {
  int tid = threadIdx.x;
  int dblk = blockIdx.x % (DINNER / 256);     // 6
  int rc   = blockIdx.x / (DINNER / 256);     // 0..255
  int d = dblk * 256 + tid;
  long r0 = (long)rc * CROWS;                 // chunks never cross batch (2048%16==0)
  int s0 = (int)(r0 % SEQL);
  const u16* xp = xzb + r0 * D2 + d;
  float w0 = 0.f, w1 = 0.f, w2 = 0.f;
  if (s0 >= 1) {
    w2 = b2f(xp[-1L * D2]);
    w1 = b2f(xp[-2L * D2]);
    w0 = b2f(xp[-3L * D2]);
  }
  float c0 = cw[d * 4 + 0], c1 = cw[d * 4 + 1];
  float c2 = cw[d * 4 + 2], c3 = cw[d * 4 + 3];
  float cbv = cb[d];
  u16* yp = xcb + r0 * DINNER + d;
  #pragma unroll 4
  for (int t = 0; t < CROWS; ++t) {
    float w3 = b2f(xp[(long)t * D2]);
    float acc = fmaf(w0, c0, fmaf(w1, c1, fmaf(w2, c2, fmaf(w3, c3, cbv))));
    float sg = 1.f / (1.f + __expf(-acc));
    yp[(long)t * DINNER] = f2b(acc * sg);
    w0 = w1; w1 = w2; w2 = w3;
  }
}

// ---------------- 7. scan phase 1: per-chunk local states + sum(delta) ------
__global__ __launch_bounds__(256) void scan_p1(const u16* __restrict__ dlt,
    const u16* __restrict__ xc, const float* __restrict__ xs,
    const float* __restrict__ Af, const int* __restrict__ flag,
    float* __restrict__ Hloc, float* __restrict__ sdl) {
  __shared__ float Bsh[CL][16];
  int tid = threadIdx.x;
  int dblk = blockIdx.x % (DINNER / 256);
  int c = (blockIdx.x / (DINNER / 256)) % NC;
  int b = blockIdx.x / ((DINNER / 256) * NC);
  int d = dblk * 256 + tid;
  long row0 = (long)b * SEQL + c * CL;
  for (int e = tid; e < CL * 16; e += 256) {
    int t = e >> 4, n = e & 15;
    Bsh[t][n] = xs[(row0 + t) * 64 + 1 + n];
  }
  bool fast = (*flag == 0);
  float Ac[16];
  if (!fast) {
    #pragma unroll
    for (int n = 0; n < 16; ++n) Ac[n] = Af[d * 16 + n];
  }
  __syncthreads();
  float h[16] = {};
  float sd = 0.f;
  const u16* dp = dlt + row0 * DINNER + d;
  const u16* xp = xc + row0 * DINNER + d;
  if (fast) {
    for (int t = 0; t < CL; ++t) {
      float dl = b2f(dp[(long)t * DINNER]);
      float xv = b2f(xp[(long)t * DINNER]);
      sd += dl;
      float dx = dl * xv;
      float E[16]; build_E_fast(dl, E);
      #pragma unroll
      for (int n = 0; n < 16; ++n) h[n] = fmaf(E[n], h[n], dx * Bsh[t][n]);
    }
  } else {
    for (int t = 0; t < CL; ++t) {
      float dl = b2f(dp[(long)t * DINNER]);
      float xv = b2f(xp[(long)t * DINNER]);
      sd += dl;
      float dx = dl * xv;
      #pragma unroll
      for (int n = 0; n < 16; ++n)
        h[n] = fmaf(__expf(dl * Ac[n]), h[n], dx * Bsh[t][n]);
    }
  }
  long base = ((long)(b * NC + c) * DINNER + d) * 16;
  #pragma unroll
  for (int n = 0; n < 16; ++n) Hloc[base + n] = h[n];
  sdl[(long)(b * NC + c) * DINNER + d] = sd;
}

// ---------------- 8. scan phase 2: carry sweep -------------------------------
__global__ __launch_bounds__(256) void scan_carry(float* __restrict__ Hloc,
    const float* __restrict__ sdl, const float* __restrict__ Af) {
  long g = (long)blockIdx.x * 256 + threadIdx.x;
  if (g >= (long)NBATCH * DINNER * 16) return;
  int n = (int)(g & 15);
  int d = (int)((g >> 4) % DINNER);
  int b = (int)(g / (16L * DINNER));
  float An = Af[d * 16 + n];
  float s = 0.f;
  for (int c = 0; c < NC; ++c) {
    long off = ((long)(b * NC + c) * DINNER + d) * 16 + n;
    float H = Hloc[off];
    float sdv = sdl[(long)(b * NC + c) * DINNER + d];
    Hloc[off] = s;
    s = fmaf(__expf(An * sdv), s, H);
  }
}

// ---------------- 9. scan phase 3: replay + fused gate -> y2 (bf16) ----------
__global__ __launch_bounds__(256) void scan_p3(const u16* __restrict__ dlt,
    const u16* __restrict__ xc, const float* __restrict__ xs,
    const float* __restrict__ Af, const int* __restrict__ flag,
    const float* __restrict__ Hloc, const u16* __restrict__ xzb,
    const float* __restrict__ Dskip, u16* __restrict__ y2) {
  __shared__ float Bsh[CL][16];
  __shared__ float Csh[CL][16];
  int tid = threadIdx.x;
  int dblk = blockIdx.x % (DINNER / 256);
  int c = (blockIdx.x / (DINNER / 256)) % NC;
  int b = blockIdx.x / ((DINNER / 256) * NC);
  int d = dblk * 256 + tid;
  long row0 = (long)b * SEQL + c * CL;
  for (int e = tid; e < CL * 16; e += 256) {
    int t = e >> 4, n = e & 15;
    long rr = row0 + t;
    Bsh[t][n] = xs[rr * 64 + 1 + n];
    Csh[t][n] = xs[rr * 64 + 17 + n];
  }
  bool fast = (*flag == 0);
  float Ac[16];
  if (!fast) {
    #pragma unroll
    for (int n = 0; n < 16; ++n) Ac[n] = Af[d * 16 + n];
  }
  __syncthreads();
  float h[16];
  long base = ((long)(b * NC + c) * DINNER + d) * 16;
  #pragma unroll
  for (int n = 0; n < 16; ++n) h[n] = Hloc[base + n];
  float Dv = Dskip[d];
  const u16* dp = dlt + row0 * DINNER + d;
  const u16* xp = xc + row0 * DINNER + d;
  const u16* zp = xzb + row0 * D2 + DINNER + d;   // z = cols 1536.. of xzb
  u16* yp = y2 + row0 * DINNER + d;
  if (fast) {
    for (int t = 0; t < CL; ++t) {
      float dl = b2f(dp[(long)t * DINNER]);
      float xv = b2f(xp[(long)t * DINNER]);
      float dx = dl * xv;
      float E[16]; build_E_fast(dl, E);
      float y = 0.f;
      #pragma unroll
      for (int n = 0; n < 16; ++n) {
        h[n] = fmaf(E[n], h[n], dx * Bsh[t][n]);
        y = fmaf(h[n], Csh[t][n], y);
      }
      float yv = fmaf(xv, Dv, y);
      float zv = b2f(zp[(long)t * D2]);
      float sz = zv / (1.f + __expf(-zv));
      yp[(long)t * DINNER] = f2b(yv * sz);
    }
  } else {
    for (int t = 0; t < CL; ++t) {
      float dl = b2f(dp[(long)t * DINNER]);
      float xv = b2f(xp[(long)t * DINNER]);
      float dx = dl * xv;
      float y = 0.f;
      #pragma unroll
      for (int n = 0; n < 16; ++n) {
        h[n] = fmaf(__expf(dl * Ac[n]), h[n], dx * Bsh[t][n]);
        y = fmaf(h[n], Csh[t][n], y);
      }
      float yv = fmaf(xv, Dv, y);
      float zv = b2f(zp[(long)t * D2]);
      float sz = zv / (1.f + __expf(-zv));
      yp[(long)t * DINNER] = f2b(yv * sz);
    }
  }
}

// ---------------- launch ----------------
extern "C" void kernel_launch(void* const* d_in, const int* in_sizes, int n_in,
                              void* d_out, int out_size, void* d_ws, size_t ws_size,
                              hipStream_t stream) {
  const float* x      = (const float*)d_in[0];
  const float* imp    = (const float*)d_in[1];
  const float* ln_g   = (const float*)d_in[2];
  const float* ln_b   = (const float*)d_in[3];
  const float* W_in   = (const float*)d_in[4];
  const float* conv_w = (const float*)d_in[5];
  const float* conv_b = (const float*)d_in[6];
  const float* W_x    = (const float*)d_in[7];
  const float* W_dt   = (const float*)d_in[8];
  const float* b_dt   = (const float*)d_in[9];
  const float* Wc1    = (const float*)d_in[10];
  const float* bc1    = (const float*)d_in[11];
  const float* Wc2    = (const float*)d_in[12];
  const float* bc2    = (const float*)d_in[13];
  const float* A_log  = (const float*)d_in[14];
  const float* Dskip  = (const float*)d_in[15];
  const float* W_out  = (const float*)d_in[16];
  float* out = (float*)d_out;

  char* ws = (char*)d_ws;
  u16*   xzb    = (u16*)  (ws);                 // 4096*3072 bf16  (25165824)
  u16*   xcb    = (u16*)  (ws + 25165824L);     // 4096*1536 bf16  (12582912)
  u16*   dltb   = (u16*)  (ws + 37748736L);     // 4096*1536 bf16  (12582912)
  float* xs64   = (float*)(ws + 50331648L);     // 4096*64 f32     (1048576)
  u16*   hid    = (u16*)  (ws + 51380224L);     // 4096*384 bf16   (3145728)
  u16*   xnb    = (u16*)  (ws + 54525952L);     // 4096*768 bf16   (6291456)
  u16*   y2     = (u16*)  (ws + 60817408L);     // 4096*1536 bf16  (12582912)
  float* Hloc   = (float*)(ws + 73400320L);     // 2*64*1536*16 f32 (12582912)
  float* sdl    = (float*)(ws + 85983232L);     // 2*64*1536 f32   (786432)
  u16*   Wt_in  = (u16*)  (ws + 86769664L);     // 3072*768 bf16   (4718592)
  u16*   Wt_c2  = (u16*)  (ws + 91488256L);     // 1536*384 bf16   (1179648)
  u16*   Wt_out = (u16*)  (ws + 92667904L);     // 768*1536 bf16   (2359296)
  u16*   Wxt    = (u16*)  (ws + 95027200L);     // 64*1536 bf16    (196608)
  float* Af     = (float*)(ws + 95223808L);     // 1536*16 f32     (98304)
  int*   flag   = (int*)  (ws + 95322112L);     // 4

  // 0. combined prep (vectorized): weight transposes + wxt + hid + LN + Af
  prep_kernel<<<2849, 256, 0, stream>>>(
      W_in, Wt_in, Wc2, Wt_c2, W_out, Wt_out, W_x, Wxt,
      imp, Wc1, bc1, hid, x, ln_g, ln_b, xnb, A_log, Af, flag);

  // 2. xz = xn @ W_in (4096 x 768 x 3072) -> xzb bf16 (x_proj | z)
  //    256x192 big tile, 512 threads, 256 blocks (1/CU)
  gemm_xz_256<<<dim3(16, 16), 512, 0, stream>>>(xnb, Wt_in, xzb);
  // 3. conv + SiLU -> xcb (bf16), rolling-window (single read of xzb)
  conv_silu_kernel<<<(DINNER / 256) * (ROWS / CROWS), 256, 0, stream>>>(xzb, conv_w, conv_b, xcb);
  // 4. x_ssm = xc @ W_x  (MFMA, N padded 33->64) -> xs64   (BM=32: 128 blocks)
  gemm_bf16<32,64,1,4,0,0><<<dim3(1, ROWS/32), 256, 0, stream>>>(
      xcb, Wxt, xs64, ROWS, 64, DINNER, nullptr, nullptr, nullptr, nullptr, nullptr);
  // 6. dlt = softplus(xs64[:,0]*Wdt+bdt) * (1+sigmoid(hid@Wc2 + bc2)) -> bf16
  gemm_bf16<64,128,1,4,2,0><<<dim3(DINNER/128, ROWS/64), 256, 0, stream>>>(
      hid, Wt_c2, nullptr, ROWS, DINNER, DHID, xs64, W_dt, b_dt, bc2, dltb);
  // 7-9. chunked scan (NC=64, CL=32)
  scan_p1<<<NBATCH * NC * (DINNER / 256), 256, 0, stream>>>(dltb, xcb, xs64, Af, flag, Hloc, sdl);
  scan_carry<<<(NBATCH * DINNER * 16) / 256, 256, 0, stream>>>(Hloc, sdl, Af);
  scan_p3<<<NBATCH * NC * (DINNER / 256), 256, 0, stream>>>(dltb, xcb, xs64, Af, flag, Hloc, xzb, Dskip, y2);
  // 10. out = y2 @ W_out + residual  (4096 x 1536 x 768)
  gemm_bf16<64,64,1,4,1,0><<<dim3(DMODEL/64, ROWS/64), 256, 0, stream>>>(
      y2, Wt_out, out, ROWS, DMODEL, DINNER, x, nullptr, nullptr, nullptr, nullptr);
}

// Round 16
// 141.889 us; speedup vs baseline: 1.2102x; 1.1206x over previous
//
#include <hip/hip_runtime.h>
#include <math.h>

#define SEQL   2048
#define NBATCH 2
#define DMODEL 768
#define DINNER 1536
#define D2     3072
#define DSTATE 16
#define DHID   384
#define ROWS   (NBATCH*SEQL)   /* 4096 */
#define NC     64              /* scan chunks */
#define CL     32              /* chunk length */
#define CROWS  16              /* conv rows per thread */
#define LN_EPSF 1e-5f

typedef unsigned short u16;
typedef short bf16x8 __attribute__((ext_vector_type(8)));
typedef float f32x4 __attribute__((ext_vector_type(4)));

// fp32 -> bf16 round-to-nearest-even
__device__ __forceinline__ u16 f2b(float x) {
  unsigned u = __float_as_uint(x);
  unsigned r = (u + 0x7FFFu + ((u >> 16) & 1u)) >> 16;
  return (u16)r;
}
__device__ __forceinline__ float b2f(u16 v) {
  return __uint_as_float((unsigned)v << 16);
}

// E[n] = exp(-dl)^(n+1), n=0..15 — 1 exp + 15 muls (log-depth ladder).
// Valid when A[d][n] == -(n+1) (device-verified via mism[]).
__device__ __forceinline__ void build_E_fast(float dl, float* E) {
  float e1 = __expf(-dl);
  float e2 = e1 * e1, e4 = e2 * e2, e8 = e4 * e4;
  E[0] = e1;      E[1] = e2;      E[2] = e2 * e1; E[3] = e4;
  E[4] = e4 * e1; E[5] = e4 * e2; E[6] = e4 * E[2]; E[7] = e8;
  E[8] = e8 * e1; E[9] = e8 * e2; E[10] = e8 * E[2]; E[11] = e8 * e4;
  E[12] = e8 * E[4]; E[13] = e8 * E[5]; E[14] = e8 * E[6]; E[15] = e8 * e8;
}

// wave-uniform fast-path check: OR of mism[0..95] == 0
__device__ __forceinline__ bool read_fast(const int* __restrict__ mism, int lane) {
  int m = 0;
  if (lane < 32) m = mism[lane] | mism[lane + 32] | mism[lane + 64];
  #pragma unroll
  for (int o = 32; o > 0; o >>= 1) m |= __shfl_xor(m, o);
  return m == 0;
}

// ---------------- combined prep kernel (vectorized) -------------------------
// 64x64 transpose tile: float4 reads (1KB/wave-instr), ushort4 writes.
__device__ __forceinline__ void tconv64_body(const float* __restrict__ src,
    u16* __restrict__ dst, int K, int N, int bx, int by, int tid) {
  __shared__ float t[64][65];
  int n0 = bx * 64, k0 = by * 64;
  int tx = tid & 15, ty = tid >> 4;   // 16 x 16
  #pragma unroll
  for (int i = 0; i < 4; ++i) {
    float4 v = *(const float4*)&src[(long)(k0 + ty + 16 * i) * N + n0 + tx * 4];
    t[ty + 16 * i][tx * 4 + 0] = v.x; t[ty + 16 * i][tx * 4 + 1] = v.y;
    t[ty + 16 * i][tx * 4 + 2] = v.z; t[ty + 16 * i][tx * 4 + 3] = v.w;
  }
  __syncthreads();
  #pragma unroll
  for (int i = 0; i < 4; ++i) {
    int n = ty + 16 * i;
    u16 o[4];
    #pragma unroll
    for (int j = 0; j < 4; ++j) o[j] = f2b(t[tx * 4 + j][n]);
    *(ushort4*)&dst[(long)(n0 + n) * K + k0 + tx * 4] = *(ushort4*)o;
  }
}

// Block ranges (2944 blocks x 256 threads):
//  [0,576)     : W_in  [768][3072]  -> Wt_in  bf16   (64x64 tiles)
//  [576,720)   : Wc2   [384][1536]  -> Wt_c2  bf16
//  [720,1008)  : W_out [1536][768]  -> Wt_out bf16
//  [1008,1056) : W_x -> Wxt [64][1536] bf16 zero-pad (bf16x8 stores)
//  [1056,1824) : hid = relu(imp*Wc1+bc1), 8 elems/thread
//  [1824,2848) : LayerNorm, wave-per-row x4 rows/block (shfl-only reduce)
//  [2848,2944) : Af = -exp(A_log), 1 elem/thread (96 blocks — no serial tail);
//                per-block mismatch count plain-stored to mism[bid] (no memset)
__global__ __launch_bounds__(256) void prep_kernel(
    const float* __restrict__ W_in,  u16* __restrict__ Wt_in,
    const float* __restrict__ Wc2,   u16* __restrict__ Wt_c2,
    const float* __restrict__ W_out, u16* __restrict__ Wt_out,
    const float* __restrict__ Wx,    u16* __restrict__ Wxt,
    const float* __restrict__ imp,   const float* __restrict__ Wc1,
    const float* __restrict__ bc1,   u16* __restrict__ hid,
    const float* __restrict__ x,     const float* __restrict__ g,
    const float* __restrict__ bta,   u16* __restrict__ xn,
    const float* __restrict__ A_log, float* __restrict__ Af,
    int* __restrict__ mism) {
  int id = blockIdx.x;
  int tid = threadIdx.x;
  if (id < 576) {
    tconv64_body(W_in, Wt_in, 768, 3072, id % 48, id / 48, tid);
  } else if (id < 720) {
    int r = id - 576;  tconv64_body(Wc2, Wt_c2, 384, 1536, r % 24, r / 24, tid);
  } else if (id < 1008) {
    int r = id - 720;  tconv64_body(W_out, Wt_out, 1536, 768, r % 12, r / 12, tid);
  } else if (id < 1056) {
    long i8 = ((long)(id - 1008) * 256 + tid) * 8;   // over 64*1536
    int n = (int)(i8 / 1536), k0 = (int)(i8 % 1536);
    u16 o[8];
    #pragma unroll
    for (int j = 0; j < 8; ++j)
      o[j] = (n < 33) ? f2b(Wx[(long)(k0 + j) * 33 + n]) : (u16)0;
    *(bf16x8*)&Wxt[i8] = *(bf16x8*)o;
  } else if (id < 1824) {
    long g8 = ((long)(id - 1056) * 256 + tid) * 8;   // over ROWS*DHID
    int j0 = (int)(g8 % DHID);
    long r = g8 / DHID;
    float im = imp[r];
    float4 wa = *(const float4*)&Wc1[j0], wb = *(const float4*)&Wc1[j0 + 4];
    float4 ba = *(const float4*)&bc1[j0], bb = *(const float4*)&bc1[j0 + 4];
    float v[8] = { fmaf(im, wa.x, ba.x), fmaf(im, wa.y, ba.y),
                   fmaf(im, wa.z, ba.z), fmaf(im, wa.w, ba.w),
                   fmaf(im, wb.x, bb.x), fmaf(im, wb.y, bb.y),
                   fmaf(im, wb.z, bb.z), fmaf(im, wb.w, bb.w) };
    u16 o[8];
    #pragma unroll
    for (int j = 0; j < 8; ++j) o[j] = f2b(v[j] > 0.f ? v[j] : 0.f);
    *(bf16x8*)&hid[g8] = *(bf16x8*)o;
  } else if (id < 2848) {
    // LN: wave per row, 4 rows per block; shfl-only reduce, all lanes active
    int wid2 = tid >> 6, lane = tid & 63;
    long r = (long)(id - 1824) * 4 + wid2;
    const float* xr = x + r * DMODEL;
    float vv[12];
    *(float4*)&vv[0] = *(const float4*)&xr[lane * 4];
    *(float4*)&vv[4] = *(const float4*)&xr[lane * 4 + 256];
    *(float4*)&vv[8] = *(const float4*)&xr[lane * 4 + 512];
    float s = 0.f;
    #pragma unroll
    for (int i = 0; i < 12; ++i) s += vv[i];
    #pragma unroll
    for (int o = 32; o > 0; o >>= 1) s += __shfl_xor(s, o);
    float mu = s * (1.f / DMODEL);
    float q = 0.f;
    #pragma unroll
    for (int i = 0; i < 12; ++i) { float dd = vv[i] - mu; q += dd * dd; }
    #pragma unroll
    for (int o = 32; o > 0; o >>= 1) q += __shfl_xor(q, o);
    float rs = rsqrtf(q * (1.f / DMODEL) + LN_EPSF);
    #pragma unroll
    for (int gq = 0; gq < 3; ++gq) {
      int col = lane * 4 + gq * 256;
      float4 gv = *(const float4*)&g[col];
      float4 bv = *(const float4*)&bta[col];
      u16 o[4];
      o[0] = f2b((vv[gq * 4 + 0] - mu) * rs * gv.x + bv.x);
      o[1] = f2b((vv[gq * 4 + 1] - mu) * rs * gv.y + bv.y);
      o[2] = f2b((vv[gq * 4 + 2] - mu) * rs * gv.z + bv.z);
      o[3] = f2b((vv[gq * 4 + 3] - mu) * rs * gv.w + bv.w);
      *(ushort4*)&xn[r * DMODEL + col] = *(ushort4*)o;
    }
  } else {
    __shared__ int scnt;
    int bi = id - 2848;             // 0..95
    int i = bi * 256 + tid;         // over 1536*16 = 24576
    if (tid == 0) scnt = 0;
    __syncthreads();
    int n = i & 15;
    float a = -expf(A_log[i]);
    Af[i] = a;
    int mm = (fabsf(a + (float)(n + 1)) > 1e-3f) ? 1 : 0;
    if (mm) atomicAdd(&scnt, 1);
    __syncthreads();
    if (tid == 0) mism[bi] = scnt;   // plain store: deterministic, no memset
  }
}

// ---------------- big-tile xz GEMM: 256x192 tile, 512 threads, 8 waves ------
// xzb[4096][3072] bf16 = xnb[4096][768] @ Wt_in[3072][768]^T, BK=64.
// Staging traffic 175MB (vs 302MB at 128^2); grid = 16x16 = 256 blocks
// (1/CU exactly). Same pre-swizzled global_load_lds staging + 2-phase dbuf.
// Chunked XCD swizzle: 32 consecutive bids/XCD -> A-panel 0.8MB L2-resident.
__global__ __launch_bounds__(512) void gemm_xz_256(
    const u16* __restrict__ A, const u16* __restrict__ Bt,
    u16* __restrict__ pz) {
  constexpr int BM = 256, BN = 192, K = 768, N = 3072;
  constexpr int HALF = (BM + BN) * 128;   // 57344 B per buffer
  __shared__ __align__(16) char smem[2 * HALF];   // 112 KB

  int tid = threadIdx.x;
  int lane = tid & 63;
  int wid = tid >> 6;                 // 0..7
  int bid = blockIdx.y * 16 + blockIdx.x;
  int swz = (bid & 7) * 32 + (bid >> 3);    // bijective, 32 bids/XCD
  int bx = swz & 15, by = swz >> 4;
  int m0 = by * BM, n0 = bx * BN;
  int wr = wid >> 2, wc = wid & 3;    // 2 x 4 wave grid; per-wave 128x48

  f32x4 acc[8][3];
  #pragma unroll
  for (int i = 0; i < 8; ++i)
    #pragma unroll
    for (int j = 0; j < 3; ++j) acc[i][j] = f32x4{0.f, 0.f, 0.f, 0.f};

  int srow = tid >> 3;                // 0..63 (row within staging round)
  int schunk = tid & 7;
  int wavebase = wid * 1024;          // wave-uniform LDS byte base
  int arow = lane & 15;
  int kgrp = lane >> 4;
  int sw = (lane & 7) << 4;

  auto stage = [&](int k0, char* base) {
    #pragma unroll
    for (int r = 0; r < 4; ++r) {     // A: 256 rows, 64 rows/round
      int row = r * 64 + srow;
      int chunk = schunk ^ (row & 7);
      const u16* g = A + (size_t)(m0 + row) * K + k0 + chunk * 8;
      __builtin_amdgcn_global_load_lds(
          (const __attribute__((address_space(1))) void*)g,
          (__attribute__((address_space(3))) void*)(base + r * 8192 + wavebase),
          16, 0, 0);
    }
    #pragma unroll
    for (int r = 0; r < 3; ++r) {     // B: 192 rows
      int row = r * 64 + srow;
      int chunk = schunk ^ (row & 7);
      const u16* g = Bt + (size_t)(n0 + row) * K + k0 + chunk * 8;
      __builtin_amdgcn_global_load_lds(
          (const __attribute__((address_space(1))) void*)g,
          (__attribute__((address_space(3))) void*)(base + BM * 128 + r * 8192 + wavebase),
          16, 0, 0);
    }
  };

  auto compute = [&](const char* base) {
    const char* Asm = base;
    const char* Bsm = base + BM * 128;
    #pragma unroll
    for (int ks = 0; ks < 2; ++ks) {
      bf16x8 af[8], bg[3];
      #pragma unroll
      for (int i = 0; i < 8; ++i) {
        int row = wr * 128 + i * 16 + arow;
        int off = row * 128 + ((((ks * 4 + kgrp) * 16)) ^ sw);
        af[i] = *(const bf16x8*)(Asm + off);
      }
      #pragma unroll
      for (int j = 0; j < 3; ++j) {
        int row = wc * 48 + j * 16 + arow;
        int off = row * 128 + ((((ks * 4 + kgrp) * 16)) ^ sw);
        bg[j] = *(const bf16x8*)(Bsm + off);
      }
      #pragma unroll
      for (int i = 0; i < 8; ++i)
        #pragma unroll
        for (int j = 0; j < 3; ++j)
          acc[i][j] = __builtin_amdgcn_mfma_f32_16x16x32_bf16(af[i], bg[j], acc[i][j], 0, 0, 0);
    }
  };

  stage(0, smem);
  asm volatile("s_waitcnt vmcnt(0)" ::: "memory");
  __builtin_amdgcn_s_barrier();
  #pragma unroll 1
  for (int t = 0; t < 12; t += 2) {
    stage((t + 1) << 6, smem + HALF);
    compute(smem);
    asm volatile("s_waitcnt vmcnt(0)" ::: "memory");
    __builtin_amdgcn_s_barrier();
    if (t + 2 < 12) stage((t + 2) << 6, smem);
    compute(smem + HALF);
    asm volatile("s_waitcnt vmcnt(0)" ::: "memory");
    __builtin_amdgcn_s_barrier();
  }

  int crow0 = m0 + wr * 128 + (lane >> 4) * 4;
  int ccol0 = n0 + wc * 48 + (lane & 15);
  #pragma unroll
  for (int i = 0; i < 8; ++i) {
    #pragma unroll
    for (int r = 0; r < 4; ++r) {
      int row = crow0 + i * 16 + r;
      #pragma unroll
      for (int j = 0; j < 3; ++j) {
        int col = ccol0 + j * 16;
        pz[(size_t)row * N + col] = f2b(acc[i][j][r]);
      }
    }
  }
}

// ---------------- bf16 MFMA GEMM: C[M][N] fp32 = A[M][K]bf16 @ Bt[N][K]bf16 --
// BM x BN tile, BK=64, 256 threads (4 waves, WGM x WGN wave grid).
// LDS layout [rows][64] bf16, XOR-swizzled: byte ^= ((row&7)<<4); staging
// pre-swizzles the *global* source so global_load_lds's linear write lands
// the swizzled layout (m173/m201 pattern).
// DOUBLE-BUFFERED 2-phase pipeline (T3 minimum template, m248-verified).
// EPI: 0 = plain fp32
//      1 = +aux residual (fp32)
//      2 = delta epilogue -> pz bf16 (p1=W_dt, p2=b_dt, p3=bc2, aux=xs64)
//      5 = full bf16 write -> pz
template<int BM, int BN, int WGM, int WGN, int EPI, int XSWZ>
__global__ __launch_bounds__(256) void gemm_bf16(
    const u16* __restrict__ A, const u16* __restrict__ Bt,
    float* __restrict__ C, int M, int N, int K, const float* __restrict__ aux,
    const float* __restrict__ p1, const float* __restrict__ p2,
    const float* __restrict__ p3, u16* __restrict__ pz) {
  constexpr int MF = BM / (16 * WGM);
  constexpr int NF = BN / (16 * WGN);
  constexpr int AR = BM / 32;   // A staging rounds
  constexpr int BR = BN / 32;   // B staging rounds
  constexpr int HALF = (BM + BN) * 128;   // bytes per buffer
  __shared__ __align__(16) char smem[2 * HALF];

  int tid = threadIdx.x;
  int lane = tid & 63;
  int wid = tid >> 6;

  int bx, by;
  if (XSWZ) {
    int nwgx = gridDim.x;
    int bid = blockIdx.y * nwgx + blockIdx.x;
    int nwg = nwgx * gridDim.y;
    int q = nwg >> 3;
    int swz = (bid & 7) * q + (bid >> 3);
    bx = swz % nwgx; by = swz / nwgx;
  } else {
    bx = blockIdx.x; by = blockIdx.y;
  }
  int m0 = by * BM, n0 = bx * BN;
  int wr = wid / WGN, wc = wid % WGN;

  f32x4 acc[MF][NF];
  #pragma unroll
  for (int i = 0; i < MF; ++i)
    #pragma unroll
    for (int j = 0; j < NF; ++j) acc[i][j] = f32x4{0.f, 0.f, 0.f, 0.f};

  int srow = tid >> 3;            // 0..31 within a staging round
  int schunk = tid & 7;           // LDS 16B-chunk index within row
  int wavebase = (tid & 192) * 16;   // wave-uniform LDS byte base (wid*1024)
  int arow = lane & 15;
  int kgrp = lane >> 4;           // 0..3
  int sw = (lane & 7) << 4;       // read-side XOR swizzle

  // stage tile (k-offset k0) into LDS buffer `base`
  auto stage = [&](int k0, char* base) {
    #pragma unroll
    for (int r = 0; r < AR; ++r) {
      int row = r * 32 + srow;
      int chunk = schunk ^ (row & 7);
      const u16* g = A + (size_t)(m0 + row) * K + k0 + chunk * 8;
      __builtin_amdgcn_global_load_lds(
          (const __attribute__((address_space(1))) void*)g,
          (__attribute__((address_space(3))) void*)(base + r * 4096 + wavebase),
          16, 0, 0);
    }
    #pragma unroll
    for (int r = 0; r < BR; ++r) {
      int row = r * 32 + srow;
      int chunk = schunk ^ (row & 7);
      const u16* g = Bt + (size_t)(n0 + row) * K + k0 + chunk * 8;
      __builtin_amdgcn_global_load_lds(
          (const __attribute__((address_space(1))) void*)g,
          (__attribute__((address_space(3))) void*)(base + BM * 128 + r * 4096 + wavebase),
          16, 0, 0);
    }
  };

  // MFMA over one staged K-tile in buffer `base`
  auto compute = [&](const char* base) {
    const char* Asm = base;
    const char* Bsm = base + BM * 128;
    #pragma unroll
    for (int ks = 0; ks < 2; ++ks) {
      bf16x8 af[MF], bg[NF];
      #pragma unroll
      for (int i = 0; i < MF; ++i) {
        int row = wr * MF * 16 + i * 16 + arow;
        int off = row * 128 + ((((ks * 4 + kgrp) * 16)) ^ sw);
        af[i] = *(const bf16x8*)(Asm + off);
      }
      #pragma unroll
      for (int j = 0; j < NF; ++j) {
        int row = wc * NF * 16 + j * 16 + arow;
        int off = row * 128 + ((((ks * 4 + kgrp) * 16)) ^ sw);
        bg[j] = *(const bf16x8*)(Bsm + off);
      }
      #pragma unroll
      for (int i = 0; i < MF; ++i)
        #pragma unroll
        for (int j = 0; j < NF; ++j)
          acc[i][j] = __builtin_amdgcn_mfma_f32_16x16x32_bf16(af[i], bg[j], acc[i][j], 0, 0, 0);
    }
  };

  int nk = K >> 6;   // even for all call sites
  stage(0, smem);
  asm volatile("s_waitcnt vmcnt(0)" ::: "memory");
  __builtin_amdgcn_s_barrier();
  for (int t = 0; t < nk; t += 2) {
    stage((t + 1) << 6, smem + HALF);        // prefetch t+1 (t+1<nk: nk even)
    compute(smem);                            // tile t
    asm volatile("s_waitcnt vmcnt(0)" ::: "memory");
    __builtin_amdgcn_s_barrier();
    if (t + 2 < nk) stage((t + 2) << 6, smem);  // prefetch t+2
    compute(smem + HALF);                     // tile t+1
    asm volatile("s_waitcnt vmcnt(0)" ::: "memory");
    __builtin_amdgcn_s_barrier();
  }

  // epilogue: D row=(lane>>4)*4+r, col=lane&15 (m89-verified)
  int crow0 = m0 + wr * MF * 16 + (lane >> 4) * 4;
  int ccol0 = n0 + wc * NF * 16 + (lane & 15);
  #pragma unroll
  for (int i = 0; i < MF; ++i) {
    #pragma unroll
    for (int r = 0; r < 4; ++r) {
      int row = crow0 + i * 16 + r;
      float araw = 0.f;
      if (EPI == 2) araw = aux[(size_t)row * 64];
      #pragma unroll
      for (int j = 0; j < NF; ++j) {
        int col = ccol0 + j * 16;
        float v = acc[i][j][r];
        if (EPI == 0) {
          C[(size_t)row * N + col] = v;
        } else if (EPI == 1) {
          C[(size_t)row * N + col] = v + aux[(size_t)row * N + col];
        } else if (EPI == 2) {
          float raw = fmaf(araw, p1[col], p2[col]);
          float sp = fmaxf(raw, 0.f) + __logf(1.f + __expf(-fabsf(raw)));
          float mod = 1.f / (1.f + __expf(-(v + p3[col])));
          pz[(size_t)row * N + col] = f2b(sp * (1.f + mod));
        } else if (EPI == 5) {
          pz[(size_t)row * N + col] = f2b(v);
        }
      }
    }
  }
}

// ---------------- 3. depthwise causal conv (k=4) + bias + SiLU ---------------
// Rolling-window: thread owns fixed d, walks CROWS s-steps; each xzb element
// read exactly once (vs 4x), coalesced across lanes. 1536 blocks.
__global__ __launch_bounds__(256) void conv_silu_kernel(const u16* __restrict__ xzb,
    const float* __restrict__ cw, const float* __restrict__ cb,
    u16* __restrict__ xcb) {
  int tid = threadIdx.x;
  int dblk = blockIdx.x % (DINNER / 256);     // 6
  int rc   = blockIdx.x / (DINNER / 256);     // 0..255
  int d = dblk * 256 + tid;
  long r0 = (long)rc * CROWS;                 // chunks never cross batch (2048%16==0)
  int s0 = (int)(r0 % SEQL);
  const u16* xp = xzb + r0 * D2 + d;
  float w0 = 0.f, w1 = 0.f, w2 = 0.f;
  if (s0 >= 1) {
    w2 = b2f(xp[-1L * D2]);
    w1 = b2f(xp[-2L * D2]);
    w0 = b2f(xp[-3L * D2]);
  }
  float c0 = cw[d * 4 + 0], c1 = cw[d * 4 + 1];
  float c2 = cw[d * 4 + 2], c3 = cw[d * 4 + 3];
  float cbv = cb[d];
  u16* yp = xcb + r0 * DINNER + d;
  #pragma unroll 4
  for (int t = 0; t < CROWS; ++t) {
    float w3 = b2f(xp[(long)t * D2]);
    float acc = fmaf(w0, c0, fmaf(w1, c1, fmaf(w2, c2, fmaf(w3, c3, cbv))));
    float sg = 1.f / (1.f + __expf(-acc));
    yp[(long)t * DINNER] = f2b(acc * sg);
    w0 = w1; w1 = w2; w2 = w3;
  }
}

// ---------------- 7. scan phase 1: per-chunk local states + sum(delta) ------
__global__ __launch_bounds__(256) void scan_p1(const u16* __restrict__ dlt,
    const u16* __restrict__ xc, const float* __restrict__ xs,
    const float* __restrict__ Af, const int* __restrict__ mism,
    float* __restrict__ Hloc, float* __restrict__ sdl) {
  __shared__ float Bsh[CL][16];
  int tid = threadIdx.x;
  int lane = tid & 63;
  int dblk = blockIdx.x % (DINNER / 256);
  int c = (blockIdx.x / (DINNER / 256)) % NC;
  int b = blockIdx.x / ((DINNER / 256) * NC);
  int d = dblk * 256 + tid;
  long row0 = (long)b * SEQL + c * CL;
  for (int e = tid; e < CL * 16; e += 256) {
    int t = e >> 4, n = e & 15;
    Bsh[t][n] = xs[(row0 + t) * 64 + 1 + n];
  }
  bool fast = read_fast(mism, lane);
  float Ac[16];
  if (!fast) {
    #pragma unroll
    for (int n = 0; n < 16; ++n) Ac[n] = Af[d * 16 + n];
  }
  __syncthreads();
  float h[16] = {};
  float sd = 0.f;
  const u16* dp = dlt + row0 * DINNER + d;
  const u16* xp = xc + row0 * DINNER + d;
  if (fast) {
    for (int t = 0; t < CL; ++t) {
      float dl = b2f(dp[(long)t * DINNER]);
      float xv = b2f(xp[(long)t * DINNER]);
      sd += dl;
      float dx = dl * xv;
      float E[16]; build_E_fast(dl, E);
      #pragma unroll
      for (int n = 0; n < 16; ++n) h[n] = fmaf(E[n], h[n], dx * Bsh[t][n]);
    }
  } else {
    for (int t = 0; t < CL; ++t) {
      float dl = b2f(dp[(long)t * DINNER]);
      float xv = b2f(xp[(long)t * DINNER]);
      sd += dl;
      float dx = dl * xv;
      #pragma unroll
      for (int n = 0; n < 16; ++n)
        h[n] = fmaf(__expf(dl * Ac[n]), h[n], dx * Bsh[t][n]);
    }
  }
  long base = ((long)(b * NC + c) * DINNER + d) * 16;
  #pragma unroll
  for (int n = 0; n < 16; ++n) Hloc[base + n] = h[n];
  sdl[(long)(b * NC + c) * DINNER + d] = sd;
}

// ---------------- 8. scan phase 2: carry sweep -------------------------------
__global__ __launch_bounds__(256) void scan_carry(float* __restrict__ Hloc,
    const float* __restrict__ sdl, const float* __restrict__ Af) {
  long g = (long)blockIdx.x * 256 + threadIdx.x;
  if (g >= (long)NBATCH * DINNER * 16) return;
  int n = (int)(g & 15);
  int d = (int)((g >> 4) % DINNER);
  int b = (int)(g / (16L * DINNER));
  float An = Af[d * 16 + n];
  float s = 0.f;
  for (int c = 0; c < NC; ++c) {
    long off = ((long)(b * NC + c) * DINNER + d) * 16 + n;
    float H = Hloc[off];
    float sdv = sdl[(long)(b * NC + c) * DINNER + d];
    Hloc[off] = s;
    s = fmaf(__expf(An * sdv), s, H);
  }
}

// ---------------- 9. scan phase 3: replay + fused gate -> y2 (bf16) ----------
__global__ __launch_bounds__(256) void scan_p3(const u16* __restrict__ dlt,
    const u16* __restrict__ xc, const float* __restrict__ xs,
    const float* __restrict__ Af, const int* __restrict__ mism,
    const float* __restrict__ Hloc, const u16* __restrict__ xzb,
    const float* __restrict__ Dskip, u16* __restrict__ y2) {
  __shared__ float Bsh[CL][16];
  __shared__ float Csh[CL][16];
  int tid = threadIdx.x;
  int lane = tid & 63;
  int dblk = blockIdx.x % (DINNER / 256);
  int c = (blockIdx.x / (DINNER / 256)) % NC;
  int b = blockIdx.x / ((DINNER / 256) * NC);
  int d = dblk * 256 + tid;
  long row0 = (long)b * SEQL + c * CL;
  for (int e = tid; e < CL * 16; e += 256) {
    int t = e >> 4, n = e & 15;
    long rr = row0 + t;
    Bsh[t][n] = xs[rr * 64 + 1 + n];
    Csh[t][n] = xs[rr * 64 + 17 + n];
  }
  bool fast = read_fast(mism, lane);
  float Ac[16];
  if (!fast) {
    #pragma unroll
    for (int n = 0; n < 16; ++n) Ac[n] = Af[d * 16 + n];
  }
  __syncthreads();
  float h[16];
  long base = ((long)(b * NC + c) * DINNER + d) * 16;
  #pragma unroll
  for (int n = 0; n < 16; ++n) h[n] = Hloc[base + n];
  float Dv = Dskip[d];
  const u16* dp = dlt + row0 * DINNER + d;
  const u16* xp = xc + row0 * DINNER + d;
  const u16* zp = xzb + row0 * D2 + DINNER + d;   // z = cols 1536.. of xzb
  u16* yp = y2 + row0 * DINNER + d;
  if (fast) {
    for (int t = 0; t < CL; ++t) {
      float dl = b2f(dp[(long)t * DINNER]);
      float xv = b2f(xp[(long)t * DINNER]);
      float dx = dl * xv;
      float E[16]; build_E_fast(dl, E);
      float y = 0.f;
      #pragma unroll
      for (int n = 0; n < 16; ++n) {
        h[n] = fmaf(E[n], h[n], dx * Bsh[t][n]);
        y = fmaf(h[n], Csh[t][n], y);
      }
      float yv = fmaf(xv, Dv, y);
      float zv = b2f(zp[(long)t * D2]);
      float sz = zv / (1.f + __expf(-zv));
      yp[(long)t * DINNER] = f2b(yv * sz);
    }
  } else {
    for (int t = 0; t < CL; ++t) {
      float dl = b2f(dp[(long)t * DINNER]);
      float xv = b2f(xp[(long)t * DINNER]);
      float dx = dl * xv;
      float y = 0.f;
      #pragma unroll
      for (int n = 0; n < 16; ++n) {
        h[n] = fmaf(__expf(dl * Ac[n]), h[n], dx * Bsh[t][n]);
        y = fmaf(h[n], Csh[t][n], y);
      }
      float yv = fmaf(xv, Dv, y);
      float zv = b2f(zp[(long)t * D2]);
      float sz = zv / (1.f + __expf(-zv));
      yp[(long)t * DINNER] = f2b(yv * sz);
    }
  }
}

// ---------------- launch ----------------
extern "C" void kernel_launch(void* const* d_in, const int* in_sizes, int n_in,
                              void* d_out, int out_size, void* d_ws, size_t ws_size,
                              hipStream_t stream) {
  const float* x      = (const float*)d_in[0];
  const float* imp    = (const float*)d_in[1];
  const float* ln_g   = (const float*)d_in[2];
  const float* ln_b   = (const float*)d_in[3];
  const float* W_in   = (const float*)d_in[4];
  const float* conv_w = (const float*)d_in[5];
  const float* conv_b = (const float*)d_in[6];
  const float* W_x    = (const float*)d_in[7];
  const float* W_dt   = (const float*)d_in[8];
  const float* b_dt   = (const float*)d_in[9];
  const float* Wc1    = (const float*)d_in[10];
  const float* bc1    = (const float*)d_in[11];
  const float* Wc2    = (const float*)d_in[12];
  const float* bc2    = (const float*)d_in[13];
  const float* A_log  = (const float*)d_in[14];
  const float* Dskip  = (const float*)d_in[15];
  const float* W_out  = (const float*)d_in[16];
  float* out = (float*)d_out;

  char* ws = (char*)d_ws;
  u16*   xzb    = (u16*)  (ws);                 // 4096*3072 bf16  (25165824)
  u16*   xcb    = (u16*)  (ws + 25165824L);     // 4096*1536 bf16  (12582912)
  u16*   dltb   = (u16*)  (ws + 37748736L);     // 4096*1536 bf16  (12582912)
  float* xs64   = (float*)(ws + 50331648L);     // 4096*64 f32     (1048576)
  u16*   hid    = (u16*)  (ws + 51380224L);     // 4096*384 bf16   (3145728)
  u16*   xnb    = (u16*)  (ws + 54525952L);     // 4096*768 bf16   (6291456)
  u16*   y2     = (u16*)  (ws + 60817408L);     // 4096*1536 bf16  (12582912)
  float* Hloc   = (float*)(ws + 73400320L);     // 2*64*1536*16 f32 (12582912)
  float* sdl    = (float*)(ws + 85983232L);     // 2*64*1536 f32   (786432)
  u16*   Wt_in  = (u16*)  (ws + 86769664L);     // 3072*768 bf16   (4718592)
  u16*   Wt_c2  = (u16*)  (ws + 91488256L);     // 1536*384 bf16   (1179648)
  u16*   Wt_out = (u16*)  (ws + 92667904L);     // 768*1536 bf16   (2359296)
  u16*   Wxt    = (u16*)  (ws + 95027200L);     // 64*1536 bf16    (196608)
  float* Af     = (float*)(ws + 95223808L);     // 1536*16 f32     (98304)
  int*   mism   = (int*)  (ws + 95322112L);     // 96 ints (384 B)

  // 0. combined prep (vectorized): weight transposes + wxt + hid + LN + Af
  prep_kernel<<<2944, 256, 0, stream>>>(
      W_in, Wt_in, Wc2, Wt_c2, W_out, Wt_out, W_x, Wxt,
      imp, Wc1, bc1, hid, x, ln_g, ln_b, xnb, A_log, Af, mism);

  // 2. xz = xn @ W_in (4096 x 768 x 3072) -> xzb bf16 (x_proj | z)
  //    256x192 big tile, 512 threads, 256 blocks (1/CU)
  gemm_xz_256<<<dim3(16, 16), 512, 0, stream>>>(xnb, Wt_in, xzb);
  // 3. conv + SiLU -> xcb (bf16), rolling-window (single read of xzb)
  conv_silu_kernel<<<(DINNER / 256) * (ROWS / CROWS), 256, 0, stream>>>(xzb, conv_w, conv_b, xcb);
  // 4. x_ssm = xc @ W_x  (MFMA, N padded 33->64) -> xs64   (BM=32: 128 blocks)
  gemm_bf16<32,64,1,4,0,0><<<dim3(1, ROWS/32), 256, 0, stream>>>(
      xcb, Wxt, xs64, ROWS, 64, DINNER, nullptr, nullptr, nullptr, nullptr, nullptr);
  // 6. dlt = softplus(xs64[:,0]*Wdt+bdt) * (1+sigmoid(hid@Wc2 + bc2)) -> bf16
  gemm_bf16<64,128,1,4,2,0><<<dim3(DINNER/128, ROWS/64), 256, 0, stream>>>(
      hid, Wt_c2, nullptr, ROWS, DINNER, DHID, xs64, W_dt, b_dt, bc2, dltb);
  // 7-9. chunked scan (NC=64, CL=32)
  scan_p1<<<NBATCH * NC * (DINNER / 256), 256, 0, stream>>>(dltb, xcb, xs64, Af, mism, Hloc, sdl);
  scan_carry<<<(NBATCH * DINNER * 16) / 256, 256, 0, stream>>>(Hloc, sdl, Af);
  scan_p3<<<NBATCH * NC * (DINNER / 256), 256, 0, stream>>>(dltb, xcb, xs64, Af, mism, Hloc, xzb, Dskip, y2);
  // 10. out = y2 @ W_out + residual  (4096 x 1536 x 768)
  gemm_bf16<64,64,1,4,1,0><<<dim3(DMODEL/64, ROWS/64), 256, 0, stream>>>(
      y2, Wt_out, out, ROWS, DMODEL, DINNER, x, nullptr, nullptr, nullptr, nullptr);
}

// Round 17
// 141.698 us; speedup vs baseline: 1.2118x; 1.0013x over previous
//
#include <hip/hip_runtime.h>
#include <math.h>

#define SEQL   2048
#define NBATCH 2
#define DMODEL 768
#define DINNER 1536
#define D2     3072
#define DSTATE 16
#define DHID   384
#define ROWS   (NBATCH*SEQL)   /* 4096 */
#define NC     64              /* scan chunks */
#define CL     32              /* chunk length */
#define CROWS  16              /* conv rows per thread */
#define LN_EPSF 1e-5f

typedef unsigned short u16;
typedef short bf16x8 __attribute__((ext_vector_type(8)));
typedef float f32x4 __attribute__((ext_vector_type(4)));

// fp32 -> bf16 round-to-nearest-even
__device__ __forceinline__ u16 f2b(float x) {
  unsigned u = __float_as_uint(x);
  unsigned r = (u + 0x7FFFu + ((u >> 16) & 1u)) >> 16;
  return (u16)r;
}
__device__ __forceinline__ float b2f(u16 v) {
  return __uint_as_float((unsigned)v << 16);
}

// E[n] = exp(-dl)^(n+1), n=0..15 — 1 exp + 15 muls (log-depth ladder).
// Valid when A[d][n] == -(n+1) (device-verified via mism[]).
__device__ __forceinline__ void build_E_fast(float dl, float* E) {
  float e1 = __expf(-dl);
  float e2 = e1 * e1, e4 = e2 * e2, e8 = e4 * e4;
  E[0] = e1;      E[1] = e2;      E[2] = e2 * e1; E[3] = e4;
  E[4] = e4 * e1; E[5] = e4 * e2; E[6] = e4 * E[2]; E[7] = e8;
  E[8] = e8 * e1; E[9] = e8 * e2; E[10] = e8 * E[2]; E[11] = e8 * e4;
  E[12] = e8 * E[4]; E[13] = e8 * E[5]; E[14] = e8 * E[6]; E[15] = e8 * e8;
}

// wave-uniform fast-path check: OR of mism[0..95] == 0
__device__ __forceinline__ bool read_fast(const int* __restrict__ mism, int lane) {
  int m = 0;
  if (lane < 32) m = mism[lane] | mism[lane + 32] | mism[lane + 64];
  #pragma unroll
  for (int o = 32; o > 0; o >>= 1) m |= __shfl_xor(m, o);
  return m == 0;
}

// ---------------- combined prep kernel (vectorized) -------------------------
// 64x64 transpose tile: float4 reads (1KB/wave-instr), ushort4 writes.
__device__ __forceinline__ void tconv64_body(const float* __restrict__ src,
    u16* __restrict__ dst, int K, int N, int bx, int by, int tid) {
  __shared__ float t[64][65];
  int n0 = bx * 64, k0 = by * 64;
  int tx = tid & 15, ty = tid >> 4;   // 16 x 16
  #pragma unroll
  for (int i = 0; i < 4; ++i) {
    float4 v = *(const float4*)&src[(long)(k0 + ty + 16 * i) * N + n0 + tx * 4];
    t[ty + 16 * i][tx * 4 + 0] = v.x; t[ty + 16 * i][tx * 4 + 1] = v.y;
    t[ty + 16 * i][tx * 4 + 2] = v.z; t[ty + 16 * i][tx * 4 + 3] = v.w;
  }
  __syncthreads();
  #pragma unroll
  for (int i = 0; i < 4; ++i) {
    int n = ty + 16 * i;
    u16 o[4];
    #pragma unroll
    for (int j = 0; j < 4; ++j) o[j] = f2b(t[tx * 4 + j][n]);
    *(ushort4*)&dst[(long)(n0 + n) * K + k0 + tx * 4] = *(ushort4*)o;
  }
}

// Block ranges (2944 blocks x 256 threads):
//  [0,576)     : W_in  [768][3072]  -> Wt_in  bf16   (64x64 tiles)
//  [576,720)   : Wc2   [384][1536]  -> Wt_c2  bf16
//  [720,1008)  : W_out [1536][768]  -> Wt_out bf16
//  [1008,1056) : W_x -> Wxt [64][1536] bf16 zero-pad (bf16x8 stores)
//  [1056,1824) : hid = relu(imp*Wc1+bc1), 8 elems/thread
//  [1824,2848) : LayerNorm, wave-per-row x4 rows/block (shfl-only reduce)
//  [2848,2944) : Af = -exp(A_log), 1 elem/thread (96 blocks — no serial tail);
//                per-block mismatch count plain-stored to mism[bid] (no memset)
__global__ __launch_bounds__(256) void prep_kernel(
    const float* __restrict__ W_in,  u16* __restrict__ Wt_in,
    const float* __restrict__ Wc2,   u16* __restrict__ Wt_c2,
    const float* __restrict__ W_out, u16* __restrict__ Wt_out,
    const float* __restrict__ Wx,    u16* __restrict__ Wxt,
    const float* __restrict__ imp,   const float* __restrict__ Wc1,
    const float* __restrict__ bc1,   u16* __restrict__ hid,
    const float* __restrict__ x,     const float* __restrict__ g,
    const float* __restrict__ bta,   u16* __restrict__ xn,
    const float* __restrict__ A_log, float* __restrict__ Af,
    int* __restrict__ mism) {
  int id = blockIdx.x;
  int tid = threadIdx.x;
  if (id < 576) {
    tconv64_body(W_in, Wt_in, 768, 3072, id % 48, id / 48, tid);
  } else if (id < 720) {
    int r = id - 576;  tconv64_body(Wc2, Wt_c2, 384, 1536, r % 24, r / 24, tid);
  } else if (id < 1008) {
    int r = id - 720;  tconv64_body(W_out, Wt_out, 1536, 768, r % 12, r / 12, tid);
  } else if (id < 1056) {
    long i8 = ((long)(id - 1008) * 256 + tid) * 8;   // over 64*1536
    int n = (int)(i8 / 1536), k0 = (int)(i8 % 1536);
    u16 o[8];
    #pragma unroll
    for (int j = 0; j < 8; ++j)
      o[j] = (n < 33) ? f2b(Wx[(long)(k0 + j) * 33 + n]) : (u16)0;
    *(bf16x8*)&Wxt[i8] = *(bf16x8*)o;
  } else if (id < 1824) {
    long g8 = ((long)(id - 1056) * 256 + tid) * 8;   // over ROWS*DHID
    int j0 = (int)(g8 % DHID);
    long r = g8 / DHID;
    float im = imp[r];
    float4 wa = *(const float4*)&Wc1[j0], wb = *(const float4*)&Wc1[j0 + 4];
    float4 ba = *(const float4*)&bc1[j0], bb = *(const float4*)&bc1[j0 + 4];
    float v[8] = { fmaf(im, wa.x, ba.x), fmaf(im, wa.y, ba.y),
                   fmaf(im, wa.z, ba.z), fmaf(im, wa.w, ba.w),
                   fmaf(im, wb.x, bb.x), fmaf(im, wb.y, bb.y),
                   fmaf(im, wb.z, bb.z), fmaf(im, wb.w, bb.w) };
    u16 o[8];
    #pragma unroll
    for (int j = 0; j < 8; ++j) o[j] = f2b(v[j] > 0.f ? v[j] : 0.f);
    *(bf16x8*)&hid[g8] = *(bf16x8*)o;
  } else if (id < 2848) {
    // LN: wave per row, 4 rows per block; shfl-only reduce, all lanes active
    int wid2 = tid >> 6, lane = tid & 63;
    long r = (long)(id - 1824) * 4 + wid2;
    const float* xr = x + r * DMODEL;
    float vv[12];
    *(float4*)&vv[0] = *(const float4*)&xr[lane * 4];
    *(float4*)&vv[4] = *(const float4*)&xr[lane * 4 + 256];
    *(float4*)&vv[8] = *(const float4*)&xr[lane * 4 + 512];
    float s = 0.f;
    #pragma unroll
    for (int i = 0; i < 12; ++i) s += vv[i];
    #pragma unroll
    for (int o = 32; o > 0; o >>= 1) s += __shfl_xor(s, o);
    float mu = s * (1.f / DMODEL);
    float q = 0.f;
    #pragma unroll
    for (int i = 0; i < 12; ++i) { float dd = vv[i] - mu; q += dd * dd; }
    #pragma unroll
    for (int o = 32; o > 0; o >>= 1) q += __shfl_xor(q, o);
    float rs = rsqrtf(q * (1.f / DMODEL) + LN_EPSF);
    #pragma unroll
    for (int gq = 0; gq < 3; ++gq) {
      int col = lane * 4 + gq * 256;
      float4 gv = *(const float4*)&g[col];
      float4 bv = *(const float4*)&bta[col];
      u16 o[4];
      o[0] = f2b((vv[gq * 4 + 0] - mu) * rs * gv.x + bv.x);
      o[1] = f2b((vv[gq * 4 + 1] - mu) * rs * gv.y + bv.y);
      o[2] = f2b((vv[gq * 4 + 2] - mu) * rs * gv.z + bv.z);
      o[3] = f2b((vv[gq * 4 + 3] - mu) * rs * gv.w + bv.w);
      *(ushort4*)&xn[r * DMODEL + col] = *(ushort4*)o;
    }
  } else {
    __shared__ int scnt;
    int bi = id - 2848;             // 0..95
    int i = bi * 256 + tid;         // over 1536*16 = 24576
    if (tid == 0) scnt = 0;
    __syncthreads();
    int n = i & 15;
    float a = -expf(A_log[i]);
    Af[i] = a;
    int mm = (fabsf(a + (float)(n + 1)) > 1e-3f) ? 1 : 0;
    if (mm) atomicAdd(&scnt, 1);
    __syncthreads();
    if (tid == 0) mism[bi] = scnt;   // plain store: deterministic, no memset
  }
}

// ---------------- big-tile xz GEMM: 256x192 tile, 512 threads, 8 waves ------
// xzb[4096][3072] bf16 = xnb[4096][768] @ Wt_in[3072][768]^T, BK=64.
// Staging traffic 175MB (vs 302MB at 128^2); grid = 16x16 = 256 blocks
// (1/CU exactly). Same pre-swizzled global_load_lds staging + 2-phase dbuf.
// Chunked XCD swizzle: 32 consecutive bids/XCD -> A-panel 0.8MB L2-resident.
__global__ __launch_bounds__(512) void gemm_xz_256(
    const u16* __restrict__ A, const u16* __restrict__ Bt,
    u16* __restrict__ pz) {
  constexpr int BM = 256, BN = 192, K = 768, N = 3072;
  constexpr int HALF = (BM + BN) * 128;   // 57344 B per buffer
  __shared__ __align__(16) char smem[2 * HALF];   // 112 KB

  int tid = threadIdx.x;
  int lane = tid & 63;
  int wid = tid >> 6;                 // 0..7
  int bid = blockIdx.y * 16 + blockIdx.x;
  int swz = (bid & 7) * 32 + (bid >> 3);    // bijective, 32 bids/XCD
  int bx = swz & 15, by = swz >> 4;
  int m0 = by * BM, n0 = bx * BN;
  int wr = wid >> 2, wc = wid & 3;    // 2 x 4 wave grid; per-wave 128x48

  f32x4 acc[8][3];
  #pragma unroll
  for (int i = 0; i < 8; ++i)
    #pragma unroll
    for (int j = 0; j < 3; ++j) acc[i][j] = f32x4{0.f, 0.f, 0.f, 0.f};

  int srow = tid >> 3;                // 0..63 (row within staging round)
  int schunk = tid & 7;
  int wavebase = wid * 1024;          // wave-uniform LDS byte base
  int arow = lane & 15;
  int kgrp = lane >> 4;
  int sw = (lane & 7) << 4;

  auto stage = [&](int k0, char* base) {
    #pragma unroll
    for (int r = 0; r < 4; ++r) {     // A: 256 rows, 64 rows/round
      int row = r * 64 + srow;
      int chunk = schunk ^ (row & 7);
      const u16* g = A + (size_t)(m0 + row) * K + k0 + chunk * 8;
      __builtin_amdgcn_global_load_lds(
          (const __attribute__((address_space(1))) void*)g,
          (__attribute__((address_space(3))) void*)(base + r * 8192 + wavebase),
          16, 0, 0);
    }
    #pragma unroll
    for (int r = 0; r < 3; ++r) {     // B: 192 rows
      int row = r * 64 + srow;
      int chunk = schunk ^ (row & 7);
      const u16* g = Bt + (size_t)(n0 + row) * K + k0 + chunk * 8;
      __builtin_amdgcn_global_load_lds(
          (const __attribute__((address_space(1))) void*)g,
          (__attribute__((address_space(3))) void*)(base + BM * 128 + r * 8192 + wavebase),
          16, 0, 0);
    }
  };

  auto compute = [&](const char* base) {
    const char* Asm = base;
    const char* Bsm = base + BM * 128;
    #pragma unroll
    for (int ks = 0; ks < 2; ++ks) {
      bf16x8 af[8], bg[3];
      #pragma unroll
      for (int i = 0; i < 8; ++i) {
        int row = wr * 128 + i * 16 + arow;
        int off = row * 128 + ((((ks * 4 + kgrp) * 16)) ^ sw);
        af[i] = *(const bf16x8*)(Asm + off);
      }
      #pragma unroll
      for (int j = 0; j < 3; ++j) {
        int row = wc * 48 + j * 16 + arow;
        int off = row * 128 + ((((ks * 4 + kgrp) * 16)) ^ sw);
        bg[j] = *(const bf16x8*)(Bsm + off);
      }
      #pragma unroll
      for (int i = 0; i < 8; ++i)
        #pragma unroll
        for (int j = 0; j < 3; ++j)
          acc[i][j] = __builtin_amdgcn_mfma_f32_16x16x32_bf16(af[i], bg[j], acc[i][j], 0, 0, 0);
    }
  };

  stage(0, smem);
  asm volatile("s_waitcnt vmcnt(0)" ::: "memory");
  __builtin_amdgcn_s_barrier();
  #pragma unroll 1
  for (int t = 0; t < 12; t += 2) {
    stage((t + 1) << 6, smem + HALF);
    compute(smem);
    asm volatile("s_waitcnt vmcnt(0)" ::: "memory");
    __builtin_amdgcn_s_barrier();
    if (t + 2 < 12) stage((t + 2) << 6, smem);
    compute(smem + HALF);
    asm volatile("s_waitcnt vmcnt(0)" ::: "memory");
    __builtin_amdgcn_s_barrier();
  }

  int crow0 = m0 + wr * 128 + (lane >> 4) * 4;
  int ccol0 = n0 + wc * 48 + (lane & 15);
  #pragma unroll
  for (int i = 0; i < 8; ++i) {
    #pragma unroll
    for (int r = 0; r < 4; ++r) {
      int row = crow0 + i * 16 + r;
      #pragma unroll
      for (int j = 0; j < 3; ++j) {
        int col = ccol0 + j * 16;
        pz[(size_t)row * N + col] = f2b(acc[i][j][r]);
      }
    }
  }
}

// ---------------- bf16 MFMA GEMM: C[M][N] fp32 = A[M][K]bf16 @ Bt[N][K]bf16 --
// BM x BN tile, BK=64, 256 threads (4 waves, WGM x WGN wave grid).
// LDS layout [rows][64] bf16, XOR-swizzled: byte ^= ((row&7)<<4); staging
// pre-swizzles the *global* source so global_load_lds's linear write lands
// the swizzled layout (m173/m201 pattern).
// DOUBLE-BUFFERED 2-phase pipeline (T3 minimum template, m248-verified).
// XSWZ=1: chunked XCD swizzle (consecutive bids -> same XCD).
// EPI: 0 = plain fp32
//      1 = +aux residual (fp32)
//      2 = delta epilogue -> pz bf16 (p1=W_dt, p2=b_dt, p3=bc2, aux=xs64)
//      5 = full bf16 write -> pz
template<int BM, int BN, int WGM, int WGN, int EPI, int XSWZ>
__global__ __launch_bounds__(256) void gemm_bf16(
    const u16* __restrict__ A, const u16* __restrict__ Bt,
    float* __restrict__ C, int M, int N, int K, const float* __restrict__ aux,
    const float* __restrict__ p1, const float* __restrict__ p2,
    const float* __restrict__ p3, u16* __restrict__ pz) {
  constexpr int MF = BM / (16 * WGM);
  constexpr int NF = BN / (16 * WGN);
  constexpr int AR = BM / 32;   // A staging rounds
  constexpr int BR = BN / 32;   // B staging rounds
  constexpr int HALF = (BM + BN) * 128;   // bytes per buffer
  __shared__ __align__(16) char smem[2 * HALF];

  int tid = threadIdx.x;
  int lane = tid & 63;
  int wid = tid >> 6;

  int bx, by;
  if (XSWZ) {
    int nwgx = gridDim.x;
    int bid = blockIdx.y * nwgx + blockIdx.x;
    int nwg = nwgx * gridDim.y;
    int q = nwg >> 3;
    int swz = (bid & 7) * q + (bid >> 3);
    bx = swz % nwgx; by = swz / nwgx;
  } else {
    bx = blockIdx.x; by = blockIdx.y;
  }
  int m0 = by * BM, n0 = bx * BN;
  int wr = wid / WGN, wc = wid % WGN;

  f32x4 acc[MF][NF];
  #pragma unroll
  for (int i = 0; i < MF; ++i)
    #pragma unroll
    for (int j = 0; j < NF; ++j) acc[i][j] = f32x4{0.f, 0.f, 0.f, 0.f};

  int srow = tid >> 3;            // 0..31 within a staging round
  int schunk = tid & 7;           // LDS 16B-chunk index within row
  int wavebase = (tid & 192) * 16;   // wave-uniform LDS byte base (wid*1024)
  int arow = lane & 15;
  int kgrp = lane >> 4;           // 0..3
  int sw = (lane & 7) << 4;       // read-side XOR swizzle

  // stage tile (k-offset k0) into LDS buffer `base`
  auto stage = [&](int k0, char* base) {
    #pragma unroll
    for (int r = 0; r < AR; ++r) {
      int row = r * 32 + srow;
      int chunk = schunk ^ (row & 7);
      const u16* g = A + (size_t)(m0 + row) * K + k0 + chunk * 8;
      __builtin_amdgcn_global_load_lds(
          (const __attribute__((address_space(1))) void*)g,
          (__attribute__((address_space(3))) void*)(base + r * 4096 + wavebase),
          16, 0, 0);
    }
    #pragma unroll
    for (int r = 0; r < BR; ++r) {
      int row = r * 32 + srow;
      int chunk = schunk ^ (row & 7);
      const u16* g = Bt + (size_t)(n0 + row) * K + k0 + chunk * 8;
      __builtin_amdgcn_global_load_lds(
          (const __attribute__((address_space(1))) void*)g,
          (__attribute__((address_space(3))) void*)(base + BM * 128 + r * 4096 + wavebase),
          16, 0, 0);
    }
  };

  // MFMA over one staged K-tile in buffer `base`
  auto compute = [&](const char* base) {
    const char* Asm = base;
    const char* Bsm = base + BM * 128;
    #pragma unroll
    for (int ks = 0; ks < 2; ++ks) {
      bf16x8 af[MF], bg[NF];
      #pragma unroll
      for (int i = 0; i < MF; ++i) {
        int row = wr * MF * 16 + i * 16 + arow;
        int off = row * 128 + ((((ks * 4 + kgrp) * 16)) ^ sw);
        af[i] = *(const bf16x8*)(Asm + off);
      }
      #pragma unroll
      for (int j = 0; j < NF; ++j) {
        int row = wc * NF * 16 + j * 16 + arow;
        int off = row * 128 + ((((ks * 4 + kgrp) * 16)) ^ sw);
        bg[j] = *(const bf16x8*)(Bsm + off);
      }
      #pragma unroll
      for (int i = 0; i < MF; ++i)
        #pragma unroll
        for (int j = 0; j < NF; ++j)
          acc[i][j] = __builtin_amdgcn_mfma_f32_16x16x32_bf16(af[i], bg[j], acc[i][j], 0, 0, 0);
    }
  };

  int nk = K >> 6;   // even for all call sites
  stage(0, smem);
  asm volatile("s_waitcnt vmcnt(0)" ::: "memory");
  __builtin_amdgcn_s_barrier();
  for (int t = 0; t < nk; t += 2) {
    stage((t + 1) << 6, smem + HALF);        // prefetch t+1 (t+1<nk: nk even)
    compute(smem);                            // tile t
    asm volatile("s_waitcnt vmcnt(0)" ::: "memory");
    __builtin_amdgcn_s_barrier();
    if (t + 2 < nk) stage((t + 2) << 6, smem);  // prefetch t+2
    compute(smem + HALF);                     // tile t+1
    asm volatile("s_waitcnt vmcnt(0)" ::: "memory");
    __builtin_amdgcn_s_barrier();
  }

  // epilogue: D row=(lane>>4)*4+r, col=lane&15 (m89-verified)
  int crow0 = m0 + wr * MF * 16 + (lane >> 4) * 4;
  int ccol0 = n0 + wc * NF * 16 + (lane & 15);
  #pragma unroll
  for (int i = 0; i < MF; ++i) {
    #pragma unroll
    for (int r = 0; r < 4; ++r) {
      int row = crow0 + i * 16 + r;
      float araw = 0.f;
      if (EPI == 2) araw = aux[(size_t)row * 64];
      #pragma unroll
      for (int j = 0; j < NF; ++j) {
        int col = ccol0 + j * 16;
        float v = acc[i][j][r];
        if (EPI == 0) {
          C[(size_t)row * N + col] = v;
        } else if (EPI == 1) {
          C[(size_t)row * N + col] = v + aux[(size_t)row * N + col];
        } else if (EPI == 2) {
          float raw = fmaf(araw, p1[col], p2[col]);
          float sp = fmaxf(raw, 0.f) + __logf(1.f + __expf(-fabsf(raw)));
          float mod = 1.f / (1.f + __expf(-(v + p3[col])));
          pz[(size_t)row * N + col] = f2b(sp * (1.f + mod));
        } else if (EPI == 5) {
          pz[(size_t)row * N + col] = f2b(v);
        }
      }
    }
  }
}

// ---------------- 3. depthwise causal conv (k=4) + bias + SiLU ---------------
// Rolling-window: thread owns fixed d, walks CROWS s-steps; each xzb element
// read exactly once (vs 4x), coalesced across lanes. 1536 blocks.
__global__ __launch_bounds__(256) void conv_silu_kernel(const u16* __restrict__ xzb,
    const float* __restrict__ cw, const float* __restrict__ cb,
    u16* __restrict__ xcb) {
  int tid = threadIdx.x;
  int dblk = blockIdx.x % (DINNER / 256);     // 6
  int rc   = blockIdx.x / (DINNER / 256);     // 0..255
  int d = dblk * 256 + tid;
  long r0 = (long)rc * CROWS;                 // chunks never cross batch (2048%16==0)
  int s0 = (int)(r0 % SEQL);
  const u16* xp = xzb + r0 * D2 + d;
  float w0 = 0.f, w1 = 0.f, w2 = 0.f;
  if (s0 >= 1) {
    w2 = b2f(xp[-1L * D2]);
    w1 = b2f(xp[-2L * D2]);
    w0 = b2f(xp[-3L * D2]);
  }
  float c0 = cw[d * 4 + 0], c1 = cw[d * 4 + 1];
  float c2 = cw[d * 4 + 2], c3 = cw[d * 4 + 3];
  float cbv = cb[d];
  u16* yp = xcb + r0 * DINNER + d;
  #pragma unroll 4
  for (int t = 0; t < CROWS; ++t) {
    float w3 = b2f(xp[(long)t * D2]);
    float acc = fmaf(w0, c0, fmaf(w1, c1, fmaf(w2, c2, fmaf(w3, c3, cbv))));
    float sg = 1.f / (1.f + __expf(-acc));
    yp[(long)t * DINNER] = f2b(acc * sg);
    w0 = w1; w1 = w2; w2 = w3;
  }
}

// ---------------- 7. scan phase 1: per-chunk local states + sum(delta) ------
__global__ __launch_bounds__(256) void scan_p1(const u16* __restrict__ dlt,
    const u16* __restrict__ xc, const float* __restrict__ xs,
    const float* __restrict__ Af, const int* __restrict__ mism,
    float* __restrict__ Hloc, float* __restrict__ sdl) {
  __shared__ float Bsh[CL][16];
  int tid = threadIdx.x;
  int lane = tid & 63;
  int dblk = blockIdx.x % (DINNER / 256);
  int c = (blockIdx.x / (DINNER / 256)) % NC;
  int b = blockIdx.x / ((DINNER / 256) * NC);
  int d = dblk * 256 + tid;
  long row0 = (long)b * SEQL + c * CL;
  for (int e = tid; e < CL * 16; e += 256) {
    int t = e >> 4, n = e & 15;
    Bsh[t][n] = xs[(row0 + t) * 64 + 1 + n];
  }
  bool fast = read_fast(mism, lane);
  float Ac[16];
  if (!fast) {
    #pragma unroll
    for (int n = 0; n < 16; ++n) Ac[n] = Af[d * 16 + n];
  }
  __syncthreads();
  float h[16] = {};
  float sd = 0.f;
  const u16* dp = dlt + row0 * DINNER + d;
  const u16* xp = xc + row0 * DINNER + d;
  if (fast) {
    for (int t = 0; t < CL; ++t) {
      float dl = b2f(dp[(long)t * DINNER]);
      float xv = b2f(xp[(long)t * DINNER]);
      sd += dl;
      float dx = dl * xv;
      float E[16]; build_E_fast(dl, E);
      #pragma unroll
      for (int n = 0; n < 16; ++n) h[n] = fmaf(E[n], h[n], dx * Bsh[t][n]);
    }
  } else {
    for (int t = 0; t < CL; ++t) {
      float dl = b2f(dp[(long)t * DINNER]);
      float xv = b2f(xp[(long)t * DINNER]);
      sd += dl;
      float dx = dl * xv;
      #pragma unroll
      for (int n = 0; n < 16; ++n)
        h[n] = fmaf(__expf(dl * Ac[n]), h[n], dx * Bsh[t][n]);
    }
  }
  long base = ((long)(b * NC + c) * DINNER + d) * 16;
  #pragma unroll
  for (int n = 0; n < 16; ++n) Hloc[base + n] = h[n];
  sdl[(long)(b * NC + c) * DINNER + d] = sd;
}

// ---------------- 8. scan phase 2: carry sweep -------------------------------
__global__ __launch_bounds__(256) void scan_carry(float* __restrict__ Hloc,
    const float* __restrict__ sdl, const float* __restrict__ Af) {
  long g = (long)blockIdx.x * 256 + threadIdx.x;
  if (g >= (long)NBATCH * DINNER * 16) return;
  int n = (int)(g & 15);
  int d = (int)((g >> 4) % DINNER);
  int b = (int)(g / (16L * DINNER));
  float An = Af[d * 16 + n];
  float s = 0.f;
  for (int c = 0; c < NC; ++c) {
    long off = ((long)(b * NC + c) * DINNER + d) * 16 + n;
    float H = Hloc[off];
    float sdv = sdl[(long)(b * NC + c) * DINNER + d];
    Hloc[off] = s;
    s = fmaf(__expf(An * sdv), s, H);
  }
}

// ---------------- 9. scan phase 3: replay + fused gate -> y2 (bf16) ----------
__global__ __launch_bounds__(256) void scan_p3(const u16* __restrict__ dlt,
    const u16* __restrict__ xc, const float* __restrict__ xs,
    const float* __restrict__ Af, const int* __restrict__ mism,
    const float* __restrict__ Hloc, const u16* __restrict__ xzb,
    const float* __restrict__ Dskip, u16* __restrict__ y2) {
  __shared__ float Bsh[CL][16];
  __shared__ float Csh[CL][16];
  int tid = threadIdx.x;
  int lane = tid & 63;
  int dblk = blockIdx.x % (DINNER / 256);
  int c = (blockIdx.x / (DINNER / 256)) % NC;
  int b = blockIdx.x / ((DINNER / 256) * NC);
  int d = dblk * 256 + tid;
  long row0 = (long)b * SEQL + c * CL;
  for (int e = tid; e < CL * 16; e += 256) {
    int t = e >> 4, n = e & 15;
    long rr = row0 + t;
    Bsh[t][n] = xs[rr * 64 + 1 + n];
    Csh[t][n] = xs[rr * 64 + 17 + n];
  }
  bool fast = read_fast(mism, lane);
  float Ac[16];
  if (!fast) {
    #pragma unroll
    for (int n = 0; n < 16; ++n) Ac[n] = Af[d * 16 + n];
  }
  __syncthreads();
  float h[16];
  long base = ((long)(b * NC + c) * DINNER + d) * 16;
  #pragma unroll
  for (int n = 0; n < 16; ++n) h[n] = Hloc[base + n];
  float Dv = Dskip[d];
  const u16* dp = dlt + row0 * DINNER + d;
  const u16* xp = xc + row0 * DINNER + d;
  const u16* zp = xzb + row0 * D2 + DINNER + d;   // z = cols 1536.. of xzb
  u16* yp = y2 + row0 * DINNER + d;
  if (fast) {
    for (int t = 0; t < CL; ++t) {
      float dl = b2f(dp[(long)t * DINNER]);
      float xv = b2f(xp[(long)t * DINNER]);
      float dx = dl * xv;
      float E[16]; build_E_fast(dl, E);
      float y = 0.f;
      #pragma unroll
      for (int n = 0; n < 16; ++n) {
        h[n] = fmaf(E[n], h[n], dx * Bsh[t][n]);
        y = fmaf(h[n], Csh[t][n], y);
      }
      float yv = fmaf(xv, Dv, y);
      float zv = b2f(zp[(long)t * D2]);
      float sz = zv / (1.f + __expf(-zv));
      yp[(long)t * DINNER] = f2b(yv * sz);
    }
  } else {
    for (int t = 0; t < CL; ++t) {
      float dl = b2f(dp[(long)t * DINNER]);
      float xv = b2f(xp[(long)t * DINNER]);
      float dx = dl * xv;
      float y = 0.f;
      #pragma unroll
      for (int n = 0; n < 16; ++n) {
        h[n] = fmaf(__expf(dl * Ac[n]), h[n], dx * Bsh[t][n]);
        y = fmaf(h[n], Csh[t][n], y);
      }
      float yv = fmaf(xv, Dv, y);
      float zv = b2f(zp[(long)t * D2]);
      float sz = zv / (1.f + __expf(-zv));
      yp[(long)t * DINNER] = f2b(yv * sz);
    }
  }
}

// ---------------- launch ----------------
extern "C" void kernel_launch(void* const* d_in, const int* in_sizes, int n_in,
                              void* d_out, int out_size, void* d_ws, size_t ws_size,
                              hipStream_t stream) {
  const float* x      = (const float*)d_in[0];
  const float* imp    = (const float*)d_in[1];
  const float* ln_g   = (const float*)d_in[2];
  const float* ln_b   = (const float*)d_in[3];
  const float* W_in   = (const float*)d_in[4];
  const float* conv_w = (const float*)d_in[5];
  const float* conv_b = (const float*)d_in[6];
  const float* W_x    = (const float*)d_in[7];
  const float* W_dt   = (const float*)d_in[8];
  const float* b_dt   = (const float*)d_in[9];
  const float* Wc1    = (const float*)d_in[10];
  const float* bc1    = (const float*)d_in[11];
  const float* Wc2    = (const float*)d_in[12];
  const float* bc2    = (const float*)d_in[13];
  const float* A_log  = (const float*)d_in[14];
  const float* Dskip  = (const float*)d_in[15];
  const float* W_out  = (const float*)d_in[16];
  float* out = (float*)d_out;

  char* ws = (char*)d_ws;
  u16*   xzb    = (u16*)  (ws);                 // 4096*3072 bf16  (25165824)
  u16*   xcb    = (u16*)  (ws + 25165824L);     // 4096*1536 bf16  (12582912)
  u16*   dltb   = (u16*)  (ws + 37748736L);     // 4096*1536 bf16  (12582912)
  float* xs64   = (float*)(ws + 50331648L);     // 4096*64 f32     (1048576)
  u16*   hid    = (u16*)  (ws + 51380224L);     // 4096*384 bf16   (3145728)
  u16*   xnb    = (u16*)  (ws + 54525952L);     // 4096*768 bf16   (6291456)
  u16*   y2     = (u16*)  (ws + 60817408L);     // 4096*1536 bf16  (12582912)
  float* Hloc   = (float*)(ws + 73400320L);     // 2*64*1536*16 f32 (12582912)
  float* sdl    = (float*)(ws + 85983232L);     // 2*64*1536 f32   (786432)
  u16*   Wt_in  = (u16*)  (ws + 86769664L);     // 3072*768 bf16   (4718592)
  u16*   Wt_c2  = (u16*)  (ws + 91488256L);     // 1536*384 bf16   (1179648)
  u16*   Wt_out = (u16*)  (ws + 92667904L);     // 768*1536 bf16   (2359296)
  u16*   Wxt    = (u16*)  (ws + 95027200L);     // 64*1536 bf16    (196608)
  float* Af     = (float*)(ws + 95223808L);     // 1536*16 f32     (98304)
  int*   mism   = (int*)  (ws + 95322112L);     // 96 ints (384 B)

  // 0. combined prep (vectorized): weight transposes + wxt + hid + LN + Af
  prep_kernel<<<2944, 256, 0, stream>>>(
      W_in, Wt_in, Wc2, Wt_c2, W_out, Wt_out, W_x, Wxt,
      imp, Wc1, bc1, hid, x, ln_g, ln_b, xnb, A_log, Af, mism);

  // 2. xz = xn @ W_in (4096 x 768 x 3072) -> xzb bf16 (x_proj | z)
  //    256x192 big tile, 512 threads, 256 blocks (1/CU)
  gemm_xz_256<<<dim3(16, 16), 512, 0, stream>>>(xnb, Wt_in, xzb);
  // 3. conv + SiLU -> xcb (bf16), rolling-window (single read of xzb)
  conv_silu_kernel<<<(DINNER / 256) * (ROWS / CROWS), 256, 0, stream>>>(xzb, conv_w, conv_b, xcb);
  // 4. x_ssm = xc @ W_x  (MFMA, N padded 33->64) -> xs64   (BM=32: 128 blocks)
  gemm_bf16<32,64,1,4,0,0><<<dim3(1, ROWS/32), 256, 0, stream>>>(
      xcb, Wxt, xs64, ROWS, 64, DINNER, nullptr, nullptr, nullptr, nullptr, nullptr);
  // 6. dlt = softplus(xs64[:,0]*Wdt+bdt) * (1+sigmoid(hid@Wc2 + bc2)) -> bf16
  gemm_bf16<64,128,1,4,2,0><<<dim3(DINNER/128, ROWS/64), 256, 0, stream>>>(
      hid, Wt_c2, nullptr, ROWS, DINNER, DHID, xs64, W_dt, b_dt, bc2, dltb);
  // 7-9. chunked scan (NC=64, CL=32)
  scan_p1<<<NBATCH * NC * (DINNER / 256), 256, 0, stream>>>(dltb, xcb, xs64, Af, mism, Hloc, sdl);
  scan_carry<<<(NBATCH * DINNER * 16) / 256, 256, 0, stream>>>(Hloc, sdl, Af);
  scan_p3<<<NBATCH * NC * (DINNER / 256), 256, 0, stream>>>(dltb, xcb, xs64, Af, mism, Hloc, xzb, Dskip, y2);
  // 10. out = y2 @ W_out + residual  (4096 x 1536 x 768)
  //     ISOLATED round-14 lever: 128x96 tile (staging 302->177MB), chunked
  //     XCD swizzle, 256 blocks, 56KB LDS -> 2 blocks/CU (8 waves/CU)
  gemm_bf16<128,96,2,2,1,1><<<dim3(DMODEL/96, ROWS/128), 256, 0, stream>>>(
      y2, Wt_out, out, ROWS, DMODEL, DINNER, x, nullptr, nullptr, nullptr, nullptr);
}

// Round 18
// 141.648 us; speedup vs baseline: 1.2122x; 1.0004x over previous
//
#include <hip/hip_runtime.h>
#include <math.h>

#define SEQL   2048
#define NBATCH 2
#define DMODEL 768
#define DINNER 1536
#define D2     3072
#define DSTATE 16
#define DHID   384
#define ROWS   (NBATCH*SEQL)   /* 4096 */
#define NC     64              /* scan chunks */
#define CL     32              /* chunk length */
#define CROWS  16              /* conv rows per thread */
#define LN_EPSF 1e-5f

typedef unsigned short u16;
typedef short bf16x8 __attribute__((ext_vector_type(8)));
typedef float f32x4 __attribute__((ext_vector_type(4)));

// fp32 -> bf16 round-to-nearest-even
__device__ __forceinline__ u16 f2b(float x) {
  unsigned u = __float_as_uint(x);
  unsigned r = (u + 0x7FFFu + ((u >> 16) & 1u)) >> 16;
  return (u16)r;
}
__device__ __forceinline__ float b2f(u16 v) {
  return __uint_as_float((unsigned)v << 16);
}

// E[n] = exp(-dl)^(n+1), n=0..15 — 1 exp + 15 muls (log-depth ladder).
// Valid when A[d][n] == -(n+1) (device-verified via mism[]).
__device__ __forceinline__ void build_E_fast(float dl, float* E) {
  float e1 = __expf(-dl);
  float e2 = e1 * e1, e4 = e2 * e2, e8 = e4 * e4;
  E[0] = e1;      E[1] = e2;      E[2] = e2 * e1; E[3] = e4;
  E[4] = e4 * e1; E[5] = e4 * e2; E[6] = e4 * E[2]; E[7] = e8;
  E[8] = e8 * e1; E[9] = e8 * e2; E[10] = e8 * E[2]; E[11] = e8 * e4;
  E[12] = e8 * E[4]; E[13] = e8 * E[5]; E[14] = e8 * E[6]; E[15] = e8 * e8;
}

// wave-uniform fast-path check: OR of mism[0..95] == 0
__device__ __forceinline__ bool read_fast(const int* __restrict__ mism, int lane) {
  int m = 0;
  if (lane < 32) m = mism[lane] | mism[lane + 32] | mism[lane + 64];
  #pragma unroll
  for (int o = 32; o > 0; o >>= 1) m |= __shfl_xor(m, o);
  return m == 0;
}

// ---------------- combined prep kernel (vectorized) -------------------------
// 64x64 transpose tile: float4 reads (1KB/wave-instr), ushort4 writes.
__device__ __forceinline__ void tconv64_body(const float* __restrict__ src,
    u16* __restrict__ dst, int K, int N, int bx, int by, int tid) {
  __shared__ float t[64][65];
  int n0 = bx * 64, k0 = by * 64;
  int tx = tid & 15, ty = tid >> 4;   // 16 x 16
  #pragma unroll
  for (int i = 0; i < 4; ++i) {
    float4 v = *(const float4*)&src[(long)(k0 + ty + 16 * i) * N + n0 + tx * 4];
    t[ty + 16 * i][tx * 4 + 0] = v.x; t[ty + 16 * i][tx * 4 + 1] = v.y;
    t[ty + 16 * i][tx * 4 + 2] = v.z; t[ty + 16 * i][tx * 4 + 3] = v.w;
  }
  __syncthreads();
  #pragma unroll
  for (int i = 0; i < 4; ++i) {
    int n = ty + 16 * i;
    u16 o[4];
    #pragma unroll
    for (int j = 0; j < 4; ++j) o[j] = f2b(t[tx * 4 + j][n]);
    *(ushort4*)&dst[(long)(n0 + n) * K + k0 + tx * 4] = *(ushort4*)o;
  }
}

// Block ranges (2944 blocks x 256 threads):
//  [0,576)     : W_in  [768][3072]  -> Wt_in  bf16   (64x64 tiles)
//  [576,720)   : Wc2   [384][1536]  -> Wt_c2  bf16
//  [720,1008)  : W_out [1536][768]  -> Wt_out bf16
//  [1008,1056) : W_x -> Wxt [64][1536] bf16 zero-pad (bf16x8 stores)
//  [1056,1824) : hid = relu(imp*Wc1+bc1), 8 elems/thread
//  [1824,2848) : LayerNorm, wave-per-row x4 rows/block (shfl-only reduce)
//  [2848,2944) : Af = -exp(A_log), 1 elem/thread (96 blocks — no serial tail);
//                per-block mismatch count plain-stored to mism[bid] (no memset)
__global__ __launch_bounds__(256) void prep_kernel(
    const float* __restrict__ W_in,  u16* __restrict__ Wt_in,
    const float* __restrict__ Wc2,   u16* __restrict__ Wt_c2,
    const float* __restrict__ W_out, u16* __restrict__ Wt_out,
    const float* __restrict__ Wx,    u16* __restrict__ Wxt,
    const float* __restrict__ imp,   const float* __restrict__ Wc1,
    const float* __restrict__ bc1,   u16* __restrict__ hid,
    const float* __restrict__ x,     const float* __restrict__ g,
    const float* __restrict__ bta,   u16* __restrict__ xn,
    const float* __restrict__ A_log, float* __restrict__ Af,
    int* __restrict__ mism) {
  int id = blockIdx.x;
  int tid = threadIdx.x;
  if (id < 576) {
    tconv64_body(W_in, Wt_in, 768, 3072, id % 48, id / 48, tid);
  } else if (id < 720) {
    int r = id - 576;  tconv64_body(Wc2, Wt_c2, 384, 1536, r % 24, r / 24, tid);
  } else if (id < 1008) {
    int r = id - 720;  tconv64_body(W_out, Wt_out, 1536, 768, r % 12, r / 12, tid);
  } else if (id < 1056) {
    long i8 = ((long)(id - 1008) * 256 + tid) * 8;   // over 64*1536
    int n = (int)(i8 / 1536), k0 = (int)(i8 % 1536);
    u16 o[8];
    #pragma unroll
    for (int j = 0; j < 8; ++j)
      o[j] = (n < 33) ? f2b(Wx[(long)(k0 + j) * 33 + n]) : (u16)0;
    *(bf16x8*)&Wxt[i8] = *(bf16x8*)o;
  } else if (id < 1824) {
    long g8 = ((long)(id - 1056) * 256 + tid) * 8;   // over ROWS*DHID
    int j0 = (int)(g8 % DHID);
    long r = g8 / DHID;
    float im = imp[r];
    float4 wa = *(const float4*)&Wc1[j0], wb = *(const float4*)&Wc1[j0 + 4];
    float4 ba = *(const float4*)&bc1[j0], bb = *(const float4*)&bc1[j0 + 4];
    float v[8] = { fmaf(im, wa.x, ba.x), fmaf(im, wa.y, ba.y),
                   fmaf(im, wa.z, ba.z), fmaf(im, wa.w, ba.w),
                   fmaf(im, wb.x, bb.x), fmaf(im, wb.y, bb.y),
                   fmaf(im, wb.z, bb.z), fmaf(im, wb.w, bb.w) };
    u16 o[8];
    #pragma unroll
    for (int j = 0; j < 8; ++j) o[j] = f2b(v[j] > 0.f ? v[j] : 0.f);
    *(bf16x8*)&hid[g8] = *(bf16x8*)o;
  } else if (id < 2848) {
    // LN: wave per row, 4 rows per block; shfl-only reduce, all lanes active
    int wid2 = tid >> 6, lane = tid & 63;
    long r = (long)(id - 1824) * 4 + wid2;
    const float* xr = x + r * DMODEL;
    float vv[12];
    *(float4*)&vv[0] = *(const float4*)&xr[lane * 4];
    *(float4*)&vv[4] = *(const float4*)&xr[lane * 4 + 256];
    *(float4*)&vv[8] = *(const float4*)&xr[lane * 4 + 512];
    float s = 0.f;
    #pragma unroll
    for (int i = 0; i < 12; ++i) s += vv[i];
    #pragma unroll
    for (int o = 32; o > 0; o >>= 1) s += __shfl_xor(s, o);
    float mu = s * (1.f / DMODEL);
    float q = 0.f;
    #pragma unroll
    for (int i = 0; i < 12; ++i) { float dd = vv[i] - mu; q += dd * dd; }
    #pragma unroll
    for (int o = 32; o > 0; o >>= 1) q += __shfl_xor(q, o);
    float rs = rsqrtf(q * (1.f / DMODEL) + LN_EPSF);
    #pragma unroll
    for (int gq = 0; gq < 3; ++gq) {
      int col = lane * 4 + gq * 256;
      float4 gv = *(const float4*)&g[col];
      float4 bv = *(const float4*)&bta[col];
      u16 o[4];
      o[0] = f2b((vv[gq * 4 + 0] - mu) * rs * gv.x + bv.x);
      o[1] = f2b((vv[gq * 4 + 1] - mu) * rs * gv.y + bv.y);
      o[2] = f2b((vv[gq * 4 + 2] - mu) * rs * gv.z + bv.z);
      o[3] = f2b((vv[gq * 4 + 3] - mu) * rs * gv.w + bv.w);
      *(ushort4*)&xn[r * DMODEL + col] = *(ushort4*)o;
    }
  } else {
    __shared__ int scnt;
    int bi = id - 2848;             // 0..95
    int i = bi * 256 + tid;         // over 1536*16 = 24576
    if (tid == 0) scnt = 0;
    __syncthreads();
    int n = i & 15;
    float a = -expf(A_log[i]);
    Af[i] = a;
    int mm = (fabsf(a + (float)(n + 1)) > 1e-3f) ? 1 : 0;
    if (mm) atomicAdd(&scnt, 1);
    __syncthreads();
    if (tid == 0) mism[bi] = scnt;   // plain store: deterministic, no memset
  }
}

// ---------------- big-tile xz GEMM: 256x192 tile, 512 threads, 8 waves ------
// xzb[4096][3072] bf16 = xnb[4096][768] @ Wt_in[3072][768]^T, BK=64.
// COUNTED-vmcnt 2-deep pipeline (T4): never drain to 0 in the main loop.
// Per-thread stage = 7 global_load_lds (4 A + 3 B); after issuing tile t+2,
// vmcnt(7) waits only for tile t+1's loads while t+2's stay in flight.
// 2 barriers/tile: A = read-done before overwrite, B = staged data visible.
// 1 block/CU (112KB LDS) -> no TLP to hide a drain, so this is the regime
// where counted-vmcnt pays (m233: 2ph drain = 72% of critical path).
__global__ __launch_bounds__(512) void gemm_xz_256(
    const u16* __restrict__ A, const u16* __restrict__ Bt,
    u16* __restrict__ pz) {
  constexpr int BM = 256, BN = 192, K = 768, N = 3072;
  constexpr int HALF = (BM + BN) * 128;   // 57344 B per buffer
  __shared__ __align__(16) char smem[2 * HALF];   // 112 KB

  int tid = threadIdx.x;
  int lane = tid & 63;
  int wid = tid >> 6;                 // 0..7
  int bid = blockIdx.y * 16 + blockIdx.x;
  int swz = (bid & 7) * 32 + (bid >> 3);    // bijective, 32 bids/XCD
  int bx = swz & 15, by = swz >> 4;
  int m0 = by * BM, n0 = bx * BN;
  int wr = wid >> 2, wc = wid & 3;    // 2 x 4 wave grid; per-wave 128x48

  f32x4 acc[8][3];
  #pragma unroll
  for (int i = 0; i < 8; ++i)
    #pragma unroll
    for (int j = 0; j < 3; ++j) acc[i][j] = f32x4{0.f, 0.f, 0.f, 0.f};

  int srow = tid >> 3;                // 0..63 (row within staging round)
  int schunk = tid & 7;
  int wavebase = wid * 1024;          // wave-uniform LDS byte base
  int arow = lane & 15;
  int kgrp = lane >> 4;
  int sw = (lane & 7) << 4;

  auto stage = [&](int k0, char* base) {
    #pragma unroll
    for (int r = 0; r < 4; ++r) {     // A: 256 rows, 64 rows/round
      int row = r * 64 + srow;
      int chunk = schunk ^ (row & 7);
      const u16* g = A + (size_t)(m0 + row) * K + k0 + chunk * 8;
      __builtin_amdgcn_global_load_lds(
          (const __attribute__((address_space(1))) void*)g,
          (__attribute__((address_space(3))) void*)(base + r * 8192 + wavebase),
          16, 0, 0);
    }
    #pragma unroll
    for (int r = 0; r < 3; ++r) {     // B: 192 rows
      int row = r * 64 + srow;
      int chunk = schunk ^ (row & 7);
      const u16* g = Bt + (size_t)(n0 + row) * K + k0 + chunk * 8;
      __builtin_amdgcn_global_load_lds(
          (const __attribute__((address_space(1))) void*)g,
          (__attribute__((address_space(3))) void*)(base + BM * 128 + r * 8192 + wavebase),
          16, 0, 0);
    }
  };

  auto compute = [&](const char* base) {
    const char* Asm = base;
    const char* Bsm = base + BM * 128;
    #pragma unroll
    for (int ks = 0; ks < 2; ++ks) {
      bf16x8 af[8], bg[3];
      #pragma unroll
      for (int i = 0; i < 8; ++i) {
        int row = wr * 128 + i * 16 + arow;
        int off = row * 128 + ((((ks * 4 + kgrp) * 16)) ^ sw);
        af[i] = *(const bf16x8*)(Asm + off);
      }
      #pragma unroll
      for (int j = 0; j < 3; ++j) {
        int row = wc * 48 + j * 16 + arow;
        int off = row * 128 + ((((ks * 4 + kgrp) * 16)) ^ sw);
        bg[j] = *(const bf16x8*)(Bsm + off);
      }
      #pragma unroll
      for (int i = 0; i < 8; ++i)
        #pragma unroll
        for (int j = 0; j < 3; ++j)
          acc[i][j] = __builtin_amdgcn_mfma_f32_16x16x32_bf16(af[i], bg[j], acc[i][j], 0, 0, 0);
    }
  };

  // prologue: tiles 0 and 1 in flight; wait only for tile 0 (7 loads of tile 1 outstanding)
  stage(0, smem);
  stage(64, smem + HALF);
  asm volatile("s_waitcnt vmcnt(7)" ::: "memory");
  __builtin_amdgcn_s_barrier();
  #pragma unroll 1
  for (int t = 0; t < 11; ++t) {
    const char* cur = (t & 1) ? (smem + HALF) : smem;
    char* nb = (t & 1) ? (smem + HALF) : smem;   // freed buffer: tile t+2 lands here
    compute(cur);                                 // tile t
    __builtin_amdgcn_s_barrier();                 // A: all waves done reading cur
    if (t + 2 < 12) {
      stage((t + 2) << 6, nb);                    // refill freed buffer
      asm volatile("s_waitcnt vmcnt(7)" ::: "memory");   // tile t+1 landed; t+2 in flight
    } else {
      asm volatile("s_waitcnt vmcnt(0)" ::: "memory");   // tail: drain tile 11
    }
    __builtin_amdgcn_s_barrier();                 // B: tile t+1 visible to all waves
  }
  compute(smem + HALF);                           // tile 11

  int crow0 = m0 + wr * 128 + (lane >> 4) * 4;
  int ccol0 = n0 + wc * 48 + (lane & 15);
  #pragma unroll
  for (int i = 0; i < 8; ++i) {
    #pragma unroll
    for (int r = 0; r < 4; ++r) {
      int row = crow0 + i * 16 + r;
      #pragma unroll
      for (int j = 0; j < 3; ++j) {
        int col = ccol0 + j * 16;
        pz[(size_t)row * N + col] = f2b(acc[i][j][r]);
      }
    }
  }
}

// ---------------- bf16 MFMA GEMM: C[M][N] fp32 = A[M][K]bf16 @ Bt[N][K]bf16 --
// BM x BN tile, BK=64, 256 threads (4 waves, WGM x WGN wave grid).
// LDS layout [rows][64] bf16, XOR-swizzled: byte ^= ((row&7)<<4); staging
// pre-swizzles the *global* source so global_load_lds's linear write lands
// the swizzled layout (m173/m201 pattern).
// DOUBLE-BUFFERED 2-phase pipeline (T3 minimum template, m248-verified).
// XSWZ=1: chunked XCD swizzle (consecutive bids -> same XCD).
// EPI: 0 = plain fp32
//      1 = +aux residual (fp32)
//      2 = delta epilogue -> pz bf16 (p1=W_dt, p2=b_dt, p3=bc2, aux=xs64)
//      5 = full bf16 write -> pz
template<int BM, int BN, int WGM, int WGN, int EPI, int XSWZ>
__global__ __launch_bounds__(256) void gemm_bf16(
    const u16* __restrict__ A, const u16* __restrict__ Bt,
    float* __restrict__ C, int M, int N, int K, const float* __restrict__ aux,
    const float* __restrict__ p1, const float* __restrict__ p2,
    const float* __restrict__ p3, u16* __restrict__ pz) {
  constexpr int MF = BM / (16 * WGM);
  constexpr int NF = BN / (16 * WGN);
  constexpr int AR = BM / 32;   // A staging rounds
  constexpr int BR = BN / 32;   // B staging rounds
  constexpr int HALF = (BM + BN) * 128;   // bytes per buffer
  __shared__ __align__(16) char smem[2 * HALF];

  int tid = threadIdx.x;
  int lane = tid & 63;
  int wid = tid >> 6;

  int bx, by;
  if (XSWZ) {
    int nwgx = gridDim.x;
    int bid = blockIdx.y * nwgx + blockIdx.x;
    int nwg = nwgx * gridDim.y;
    int q = nwg >> 3;
    int swz = (bid & 7) * q + (bid >> 3);
    bx = swz % nwgx; by = swz / nwgx;
  } else {
    bx = blockIdx.x; by = blockIdx.y;
  }
  int m0 = by * BM, n0 = bx * BN;
  int wr = wid / WGN, wc = wid % WGN;

  f32x4 acc[MF][NF];
  #pragma unroll
  for (int i = 0; i < MF; ++i)
    #pragma unroll
    for (int j = 0; j < NF; ++j) acc[i][j] = f32x4{0.f, 0.f, 0.f, 0.f};

  int srow = tid >> 3;            // 0..31 within a staging round
  int schunk = tid & 7;           // LDS 16B-chunk index within row
  int wavebase = (tid & 192) * 16;   // wave-uniform LDS byte base (wid*1024)
  int arow = lane & 15;
  int kgrp = lane >> 4;           // 0..3
  int sw = (lane & 7) << 4;       // read-side XOR swizzle

  // stage tile (k-offset k0) into LDS buffer `base`
  auto stage = [&](int k0, char* base) {
    #pragma unroll
    for (int r = 0; r < AR; ++r) {
      int row = r * 32 + srow;
      int chunk = schunk ^ (row & 7);
      const u16* g = A + (size_t)(m0 + row) * K + k0 + chunk * 8;
      __builtin_amdgcn_global_load_lds(
          (const __attribute__((address_space(1))) void*)g,
          (__attribute__((address_space(3))) void*)(base + r * 4096 + wavebase),
          16, 0, 0);
    }
    #pragma unroll
    for (int r = 0; r < BR; ++r) {
      int row = r * 32 + srow;
      int chunk = schunk ^ (row & 7);
      const u16* g = Bt + (size_t)(n0 + row) * K + k0 + chunk * 8;
      __builtin_amdgcn_global_load_lds(
          (const __attribute__((address_space(1))) void*)g,
          (__attribute__((address_space(3))) void*)(base + BM * 128 + r * 4096 + wavebase),
          16, 0, 0);
    }
  };

  // MFMA over one staged K-tile in buffer `base`
  auto compute = [&](const char* base) {
    const char* Asm = base;
    const char* Bsm = base + BM * 128;
    #pragma unroll
    for (int ks = 0; ks < 2; ++ks) {
      bf16x8 af[MF], bg[NF];
      #pragma unroll
      for (int i = 0; i < MF; ++i) {
        int row = wr * MF * 16 + i * 16 + arow;
        int off = row * 128 + ((((ks * 4 + kgrp) * 16)) ^ sw);
        af[i] = *(const bf16x8*)(Asm + off);
      }
      #pragma unroll
      for (int j = 0; j < NF; ++j) {
        int row = wc * NF * 16 + j * 16 + arow;
        int off = row * 128 + ((((ks * 4 + kgrp) * 16)) ^ sw);
        bg[j] = *(const bf16x8*)(Bsm + off);
      }
      #pragma unroll
      for (int i = 0; i < MF; ++i)
        #pragma unroll
        for (int j = 0; j < NF; ++j)
          acc[i][j] = __builtin_amdgcn_mfma_f32_16x16x32_bf16(af[i], bg[j], acc[i][j], 0, 0, 0);
    }
  };

  int nk = K >> 6;   // even for all call sites
  stage(0, smem);
  asm volatile("s_waitcnt vmcnt(0)" ::: "memory");
  __builtin_amdgcn_s_barrier();
  for (int t = 0; t < nk; t += 2) {
    stage((t + 1) << 6, smem + HALF);        // prefetch t+1 (t+1<nk: nk even)
    compute(smem);                            // tile t
    asm volatile("s_waitcnt vmcnt(0)" ::: "memory");
    __builtin_amdgcn_s_barrier();
    if (t + 2 < nk) stage((t + 2) << 6, smem);  // prefetch t+2
    compute(smem + HALF);                     // tile t+1
    asm volatile("s_waitcnt vmcnt(0)" ::: "memory");
    __builtin_amdgcn_s_barrier();
  }

  // epilogue: D row=(lane>>4)*4+r, col=lane&15 (m89-verified)
  int crow0 = m0 + wr * MF * 16 + (lane >> 4) * 4;
  int ccol0 = n0 + wc * NF * 16 + (lane & 15);
  #pragma unroll
  for (int i = 0; i < MF; ++i) {
    #pragma unroll
    for (int r = 0; r < 4; ++r) {
      int row = crow0 + i * 16 + r;
      float araw = 0.f;
      if (EPI == 2) araw = aux[(size_t)row * 64];
      #pragma unroll
      for (int j = 0; j < NF; ++j) {
        int col = ccol0 + j * 16;
        float v = acc[i][j][r];
        if (EPI == 0) {
          C[(size_t)row * N + col] = v;
        } else if (EPI == 1) {
          C[(size_t)row * N + col] = v + aux[(size_t)row * N + col];
        } else if (EPI == 2) {
          float raw = fmaf(araw, p1[col], p2[col]);
          float sp = fmaxf(raw, 0.f) + __logf(1.f + __expf(-fabsf(raw)));
          float mod = 1.f / (1.f + __expf(-(v + p3[col])));
          pz[(size_t)row * N + col] = f2b(sp * (1.f + mod));
        } else if (EPI == 5) {
          pz[(size_t)row * N + col] = f2b(v);
        }
      }
    }
  }
}

// ---------------- 3. depthwise causal conv (k=4) + bias + SiLU ---------------
// Rolling-window: thread owns fixed d, walks CROWS s-steps; each xzb element
// read exactly once (vs 4x), coalesced across lanes. 1536 blocks.
__global__ __launch_bounds__(256) void conv_silu_kernel(const u16* __restrict__ xzb,
    const float* __restrict__ cw, const float* __restrict__ cb,
    u16* __restrict__ xcb) {
  int tid = threadIdx.x;
  int dblk = blockIdx.x % (DINNER / 256);     // 6
  int rc   = blockIdx.x / (DINNER / 256);     // 0..255
  int d = dblk * 256 + tid;
  long r0 = (long)rc * CROWS;                 // chunks never cross batch (2048%16==0)
  int s0 = (int)(r0 % SEQL);
  const u16* xp = xzb + r0 * D2 + d;
  float w0 = 0.f, w1 = 0.f, w2 = 0.f;
  if (s0 >= 1) {
    w2 = b2f(xp[-1L * D2]);
    w1 = b2f(xp[-2L * D2]);
    w0 = b2f(xp[-3L * D2]);
  }
  float c0 = cw[d * 4 + 0], c1 = cw[d * 4 + 1];
  float c2 = cw[d * 4 + 2], c3 = cw[d * 4 + 3];
  float cbv = cb[d];
  u16* yp = xcb + r0 * DINNER + d;
  #pragma unroll 4
  for (int t = 0; t < CROWS; ++t) {
    float w3 = b2f(xp[(long)t * D2]);
    float acc = fmaf(w0, c0, fmaf(w1, c1, fmaf(w2, c2, fmaf(w3, c3, cbv))));
    float sg = 1.f / (1.f + __expf(-acc));
    yp[(long)t * DINNER] = f2b(acc * sg);
    w0 = w1; w1 = w2; w2 = w3;
  }
}

// ---------------- 7. scan phase 1: per-chunk local states + sum(delta) ------
__global__ __launch_bounds__(256) void scan_p1(const u16* __restrict__ dlt,
    const u16* __restrict__ xc, const float* __restrict__ xs,
    const float* __restrict__ Af, const int* __restrict__ mism,
    float* __restrict__ Hloc, float* __restrict__ sdl) {
  __shared__ float Bsh[CL][16];
  int tid = threadIdx.x;
  int lane = tid & 63;
  int dblk = blockIdx.x % (DINNER / 256);
  int c = (blockIdx.x / (DINNER / 256)) % NC;
  int b = blockIdx.x / ((DINNER / 256) * NC);
  int d = dblk * 256 + tid;
  long row0 = (long)b * SEQL + c * CL;
  for (int e = tid; e < CL * 16; e += 256) {
    int t = e >> 4, n = e & 15;
    Bsh[t][n] = xs[(row0 + t) * 64 + 1 + n];
  }
  bool fast = read_fast(mism, lane);
  float Ac[16];
  if (!fast) {
    #pragma unroll
    for (int n = 0; n < 16; ++n) Ac[n] = Af[d * 16 + n];
  }
  __syncthreads();
  float h[16] = {};
  float sd = 0.f;
  const u16* dp = dlt + row0 * DINNER + d;
  const u16* xp = xc + row0 * DINNER + d;
  if (fast) {
    for (int t = 0; t < CL; ++t) {
      float dl = b2f(dp[(long)t * DINNER]);
      float xv = b2f(xp[(long)t * DINNER]);
      sd += dl;
      float dx = dl * xv;
      float E[16]; build_E_fast(dl, E);
      #pragma unroll
      for (int n = 0; n < 16; ++n) h[n] = fmaf(E[n], h[n], dx * Bsh[t][n]);
    }
  } else {
    for (int t = 0; t < CL; ++t) {
      float dl = b2f(dp[(long)t * DINNER]);
      float xv = b2f(xp[(long)t * DINNER]);
      sd += dl;
      float dx = dl * xv;
      #pragma unroll
      for (int n = 0; n < 16; ++n)
        h[n] = fmaf(__expf(dl * Ac[n]), h[n], dx * Bsh[t][n]);
    }
  }
  long base = ((long)(b * NC + c) * DINNER + d) * 16;
  #pragma unroll
  for (int n = 0; n < 16; ++n) Hloc[base + n] = h[n];
  sdl[(long)(b * NC + c) * DINNER + d] = sd;
}

// ---------------- 8. scan phase 2: carry sweep -------------------------------
__global__ __launch_bounds__(256) void scan_carry(float* __restrict__ Hloc,
    const float* __restrict__ sdl, const float* __restrict__ Af) {
  long g = (long)blockIdx.x * 256 + threadIdx.x;
  if (g >= (long)NBATCH * DINNER * 16) return;
  int n = (int)(g & 15);
  int d = (int)((g >> 4) % DINNER);
  int b = (int)(g / (16L * DINNER));
  float An = Af[d * 16 + n];
  float s = 0.f;
  for (int c = 0; c < NC; ++c) {
    long off = ((long)(b * NC + c) * DINNER + d) * 16 + n;
    float H = Hloc[off];
    float sdv = sdl[(long)(b * NC + c) * DINNER + d];
    Hloc[off] = s;
    s = fmaf(__expf(An * sdv), s, H);
  }
}

// ---------------- 9. scan phase 3: replay + fused gate -> y2 (bf16) ----------
__global__ __launch_bounds__(256) void scan_p3(const u16* __restrict__ dlt,
    const u16* __restrict__ xc, const float* __restrict__ xs,
    const float* __restrict__ Af, const int* __restrict__ mism,
    const float* __restrict__ Hloc, const u16* __restrict__ xzb,
    const float* __restrict__ Dskip, u16* __restrict__ y2) {
  __shared__ float Bsh[CL][16];
  __shared__ float Csh[CL][16];
  int tid = threadIdx.x;
  int lane = tid & 63;
  int dblk = blockIdx.x % (DINNER / 256);
  int c = (blockIdx.x / (DINNER / 256)) % NC;
  int b = blockIdx.x / ((DINNER / 256) * NC);
  int d = dblk * 256 + tid;
  long row0 = (long)b * SEQL + c * CL;
  for (int e = tid; e < CL * 16; e += 256) {
    int t = e >> 4, n = e & 15;
    long rr = row0 + t;
    Bsh[t][n] = xs[rr * 64 + 1 + n];
    Csh[t][n] = xs[rr * 64 + 17 + n];
  }
  bool fast = read_fast(mism, lane);
  float Ac[16];
  if (!fast) {
    #pragma unroll
    for (int n = 0; n < 16; ++n) Ac[n] = Af[d * 16 + n];
  }
  __syncthreads();
  float h[16];
  long base = ((long)(b * NC + c) * DINNER + d) * 16;
  #pragma unroll
  for (int n = 0; n < 16; ++n) h[n] = Hloc[base + n];
  float Dv = Dskip[d];
  const u16* dp = dlt + row0 * DINNER + d;
  const u16* xp = xc + row0 * DINNER + d;
  const u16* zp = xzb + row0 * D2 + DINNER + d;   // z = cols 1536.. of xzb
  u16* yp = y2 + row0 * DINNER + d;
  if (fast) {
    for (int t = 0; t < CL; ++t) {
      float dl = b2f(dp[(long)t * DINNER]);
      float xv = b2f(xp[(long)t * DINNER]);
      float dx = dl * xv;
      float E[16]; build_E_fast(dl, E);
      float y = 0.f;
      #pragma unroll
      for (int n = 0; n < 16; ++n) {
        h[n] = fmaf(E[n], h[n], dx * Bsh[t][n]);
        y = fmaf(h[n], Csh[t][n], y);
      }
      float yv = fmaf(xv, Dv, y);
      float zv = b2f(zp[(long)t * D2]);
      float sz = zv / (1.f + __expf(-zv));
      yp[(long)t * DINNER] = f2b(yv * sz);
    }
  } else {
    for (int t = 0; t < CL; ++t) {
      float dl = b2f(dp[(long)t * DINNER]);
      float xv = b2f(xp[(long)t * DINNER]);
      float dx = dl * xv;
      float y = 0.f;
      #pragma unroll
      for (int n = 0; n < 16; ++n) {
        h[n] = fmaf(__expf(dl * Ac[n]), h[n], dx * Bsh[t][n]);
        y = fmaf(h[n], Csh[t][n], y);
      }
      float yv = fmaf(xv, Dv, y);
      float zv = b2f(zp[(long)t * D2]);
      float sz = zv / (1.f + __expf(-zv));
      yp[(long)t * DINNER] = f2b(yv * sz);
    }
  }
}

// ---------------- launch ----------------
extern "C" void kernel_launch(void* const* d_in, const int* in_sizes, int n_in,
                              void* d_out, int out_size, void* d_ws, size_t ws_size,
                              hipStream_t stream) {
  const float* x      = (const float*)d_in[0];
  const float* imp    = (const float*)d_in[1];
  const float* ln_g   = (const float*)d_in[2];
  const float* ln_b   = (const float*)d_in[3];
  const float* W_in   = (const float*)d_in[4];
  const float* conv_w = (const float*)d_in[5];
  const float* conv_b = (const float*)d_in[6];
  const float* W_x    = (const float*)d_in[7];
  const float* W_dt   = (const float*)d_in[8];
  const float* b_dt   = (const float*)d_in[9];
  const float* Wc1    = (const float*)d_in[10];
  const float* bc1    = (const float*)d_in[11];
  const float* Wc2    = (const float*)d_in[12];
  const float* bc2    = (const float*)d_in[13];
  const float* A_log  = (const float*)d_in[14];
  const float* Dskip  = (const float*)d_in[15];
  const float* W_out  = (const float*)d_in[16];
  float* out = (float*)d_out;

  char* ws = (char*)d_ws;
  u16*   xzb    = (u16*)  (ws);                 // 4096*3072 bf16  (25165824)
  u16*   xcb    = (u16*)  (ws + 25165824L);     // 4096*1536 bf16  (12582912)
  u16*   dltb   = (u16*)  (ws + 37748736L);     // 4096*1536 bf16  (12582912)
  float* xs64   = (float*)(ws + 50331648L);     // 4096*64 f32     (1048576)
  u16*   hid    = (u16*)  (ws + 51380224L);     // 4096*384 bf16   (3145728)
  u16*   xnb    = (u16*)  (ws + 54525952L);     // 4096*768 bf16   (6291456)
  u16*   y2     = (u16*)  (ws + 60817408L);     // 4096*1536 bf16  (12582912)
  float* Hloc   = (float*)(ws + 73400320L);     // 2*64*1536*16 f32 (12582912)
  float* sdl    = (float*)(ws + 85983232L);     // 2*64*1536 f32   (786432)
  u16*   Wt_in  = (u16*)  (ws + 86769664L);     // 3072*768 bf16   (4718592)
  u16*   Wt_c2  = (u16*)  (ws + 91488256L);     // 1536*384 bf16   (1179648)
  u16*   Wt_out = (u16*)  (ws + 92667904L);     // 768*1536 bf16   (2359296)
  u16*   Wxt    = (u16*)  (ws + 95027200L);     // 64*1536 bf16    (196608)
  float* Af     = (float*)(ws + 95223808L);     // 1536*16 f32     (98304)
  int*   mism   = (int*)  (ws + 95322112L);     // 96 ints (384 B)

  // 0. combined prep (vectorized): weight transposes + wxt + hid + LN + Af
  prep_kernel<<<2944, 256, 0, stream>>>(
      W_in, Wt_in, Wc2, Wt_c2, W_out, Wt_out, W_x, Wxt,
      imp, Wc1, bc1, hid, x, ln_g, ln_b, xnb, A_log, Af, mism);

  // 2. xz = xn @ W_in (4096 x 768 x 3072) -> xzb bf16 (x_proj | z)
  //    256x192 big tile, counted-vmcnt pipeline, 256 blocks (1/CU)
  gemm_xz_256<<<dim3(16, 16), 512, 0, stream>>>(xnb, Wt_in, xzb);
  // 3. conv + SiLU -> xcb (bf16), rolling-window (single read of xzb)
  conv_silu_kernel<<<(DINNER / 256) * (ROWS / CROWS), 256, 0, stream>>>(xzb, conv_w, conv_b, xcb);
  // 4. x_ssm = xc @ W_x  (MFMA, N padded 33->64) -> xs64   (BM=32: 128 blocks)
  gemm_bf16<32,64,1,4,0,0><<<dim3(1, ROWS/32), 256, 0, stream>>>(
      xcb, Wxt, xs64, ROWS, 64, DINNER, nullptr, nullptr, nullptr, nullptr, nullptr);
  // 6. dlt = softplus(xs64[:,0]*Wdt+bdt) * (1+sigmoid(hid@Wc2 + bc2)) -> bf16
  gemm_bf16<64,128,1,4,2,0><<<dim3(DINNER/128, ROWS/64), 256, 0, stream>>>(
      hid, Wt_c2, nullptr, ROWS, DINNER, DHID, xs64, W_dt, b_dt, bc2, dltb);
  // 7-9. chunked scan (NC=64, CL=32)
  scan_p1<<<NBATCH * NC * (DINNER / 256), 256, 0, stream>>>(dltb, xcb, xs64, Af, mism, Hloc, sdl);
  scan_carry<<<(NBATCH * DINNER * 16) / 256, 256, 0, stream>>>(Hloc, sdl, Af);
  scan_p3<<<NBATCH * NC * (DINNER / 256), 256, 0, stream>>>(dltb, xcb, xs64, Af, mism, Hloc, xzb, Dskip, y2);
  // 10. out = y2 @ W_out + residual  (4096 x 1536 x 768)
  gemm_bf16<128,96,2,2,1,1><<<dim3(DMODEL/96, ROWS/128), 256, 0, stream>>>(
      y2, Wt_out, out, ROWS, DMODEL, DINNER, x, nullptr, nullptr, nullptr, nullptr);
}